// Round 12
// baseline (178.997 us; speedup 1.0000x reference)
//
#include <hip/hip_runtime.h>
#include <hip/hip_bf16.h>
#include <math.h>

#define Bn 32
#define Ln 4096
#define ROWS 16384
#define LR 136
#define SLOPEC 0.2f
#define NEGSENT -1e30f
// Copy plan (8,388,608 f32x4 slots total):
//  linear [0, 6291456) = batches 0-23 full:  k_pre 1024x1536 | k_pq 1088x2048 | k_combine 4096x608
//  heads of batches 24-31 (rows<128, 65536 slots): k_pre extra 1024x64
//  tails of batches 24-31 (rows>=128, 8x253952): k_edges 4096x496 (batch=24+(bid>>9))
// k_edges atomics touch ONLY rows<128 (centers) -> disjoint from its copy range.

typedef __attribute__((ext_vector_type(8))) short bf16x8;
typedef __attribute__((ext_vector_type(4))) float f32x4;

__device__ __forceinline__ void copy_lin(const float* __restrict__ emb,
        float* __restrict__ out, long start, int count, int tid) {
    const f32x4* s4 = (const f32x4*)emb;
    f32x4* d4 = (f32x4*)out;
    for (int i = tid; i < count; i += 256)
        d4[start + i] = s4[start + i];
}

__device__ __forceinline__ f32x4 leaky4(f32x4 v) {
    f32x4 r;
    r.x = v.x >= 0.f ? v.x : SLOPEC * v.x;
    r.y = v.y >= 0.f ? v.y : SLOPEC * v.y;
    r.z = v.z >= 0.f ? v.z : SLOPEC * v.z;
    r.w = v.w >= 0.f ? v.w : SLOPEC * v.w;
    return r;
}

// ---------------- pre: WtGT(bf16), emb135h(bf16), W3g, btg, ae, ve, keys, bflag
//                  + linear copy share + heads copy (rows<128 of batches 24-31) ----------------
__global__ __launch_bounds__(256) void k_pre(const float* __restrict__ Wtrip,
        const float* __restrict__ btrip, const float* __restrict__ Eemb,
        const float* __restrict__ Wattn, const float* __restrict__ Wgat,
        const int* __restrict__ ast, const int* __restrict__ alen,
        const int* __restrict__ ost, const int* __restrict__ olen,
        const float* __restrict__ emb, float* __restrict__ out,
        __hip_bfloat16* __restrict__ WtGT, __hip_bfloat16* __restrict__ embh,
        float* __restrict__ W3g, float* __restrict__ btg,
        float* __restrict__ ae, float* __restrict__ ve,
        int* __restrict__ keys, int* __restrict__ bflag) {
    int bid = blockIdx.x, tid = threadIdx.x;
    copy_lin(emb, out, (long)bid * 1536, 1536, tid);
    {   // heads: rows<128 of batches 24-31
        const f32x4* s4 = (const f32x4*)emb;
        f32x4* d4 = (f32x4*)out;
        #pragma unroll
        for (int i = 0; i < 64; i += 256) {}   // (kept simple below)
        int s2base = bid * 64;
        #pragma unroll
        for (int i = tid; i < 64; i += 256) {
            long s2 = s2base + i;
            long slot = ((24L + (s2 >> 13)) << 18) | (s2 & 8191);
            d4[slot] = s4[slot];
        }
    }
    __shared__ float Als[32][68];
    __shared__ float Bls[32][64];
    __shared__ float red[4];
    __shared__ float vr0[8][32], vr1[8][32];
    if (bid < 32) {
        // WtG[mat] = Wtrip[mat*256:(mat+1)*256] @ Wgat[0:256]; store bf16 transposed
        int mat = bid >> 4, t = bid & 15;
        int m0 = (t >> 2) << 6, n0 = (t & 3) << 6;
        const float* A = Wtrip + mat * 65536;
        int r0 = (tid & 15) << 2, c0 = (tid >> 4) << 2;
        float acc[4][4] = {};
        for (int kk = 0; kk < 256; kk += 32) {
            __syncthreads();
            #pragma unroll
            for (int p = 0; p < 2; ++p) {
                int idx = tid + (p << 8);
                int row = idx >> 3, kq = (idx & 7) << 2;
                const float4 v = *(const float4*)(A + (size_t)(m0 + row) * 256 + kk + kq);
                Als[kq + 0][row] = v.x; Als[kq + 1][row] = v.y;
                Als[kq + 2][row] = v.z; Als[kq + 3][row] = v.w;
            }
            #pragma unroll
            for (int p = 0; p < 2; ++p) {
                int idx = tid + (p << 8);
                int k = idx >> 4, hq = (idx & 15) << 2;
                *(float4*)(&Bls[k][hq]) = *(const float4*)(Wgat + (size_t)(kk + k) * 256 + n0 + hq);
            }
            __syncthreads();
            #pragma unroll
            for (int k = 0; k < 32; ++k) {
                float4 a  = *(const float4*)(&Als[k][r0]);
                float4 bv = *(const float4*)(&Bls[k][c0]);
                acc[0][0] += a.x*bv.x; acc[0][1] += a.x*bv.y; acc[0][2] += a.x*bv.z; acc[0][3] += a.x*bv.w;
                acc[1][0] += a.y*bv.x; acc[1][1] += a.y*bv.y; acc[1][2] += a.y*bv.z; acc[1][3] += a.y*bv.w;
                acc[2][0] += a.z*bv.x; acc[2][1] += a.z*bv.y; acc[2][2] += a.z*bv.z; acc[2][3] += a.z*bv.w;
                acc[3][0] += a.w*bv.x; acc[3][1] += a.w*bv.y; acc[3][2] += a.w*bv.z; acc[3][3] += a.w*bv.w;
            }
        }
        #pragma unroll
        for (int i = 0; i < 4; ++i)
            #pragma unroll
            for (int j = 0; j < 4; ++j)
                WtGT[(size_t)(mat * 256 + n0 + c0 + j) * 256 + m0 + r0 + i] =
                    __float2bfloat16(acc[i][j]);
    } else if (bid == 32) {
        float s = 0.f;
        for (int k = 0; k < 256; ++k) s += btrip[k] * Wgat[(size_t)k * 256 + tid];
        btg[tid] = s;
    } else if (bid == 33) {
        if (tid < Bn) bflag[tid] = 0;
        #pragma unroll
        for (int e = 0; e < 2; ++e) {
            float x = Eemb[e * 256 + tid];
            float lx = x >= 0.f ? x : SLOPEC * x;
            float s = lx * Wattn[512 + tid];
            #pragma unroll
            for (int o = 32; o; o >>= 1) s += __shfl_down(s, o);
            if ((tid & 63) == 0) red[tid >> 6] = s;
            __syncthreads();
            if (tid == 0) ae[e] = red[0] + red[1] + red[2] + red[3];
            __syncthreads();
        }
    } else if (bid < 37) {
        int s = bid - 34;
        float acc = 0.f;
        for (int k = 0; k < 256; ++k)
            acc += Wtrip[(size_t)(512 + s) * 256 + k] * Wgat[(size_t)k * 256 + tid];
        W3g[s * 256 + tid] = acc;
    } else if (bid < 45) {
        int j = bid - 37;
        int n0 = j << 5;
        int nl = tid & 31, kg = tid >> 5;
        float p0 = 0.f, p1 = 0.f;
        for (int kk = 0; kk < 32; ++kk) {
            int k = (kg << 5) + kk;
            float w = Wgat[(size_t)(256 + k) * 256 + n0 + nl];
            p0 += Eemb[k] * w;
            p1 += Eemb[256 + k] * w;
        }
        vr0[kg][nl] = p0; vr1[kg][nl] = p1;
        __syncthreads();
        if (tid < 32) {
            float s0 = 0.f, s1 = 0.f;
            #pragma unroll
            for (int g = 0; g < 8; ++g) { s0 += vr0[g][tid]; s1 += vr1[g][tid]; }
            ve[n0 + tid] = s0;
            ve[256 + n0 + tid] = s1;
        }
    } else if (bid < 109) {
        int row = (bid - 45) * 256 + tid;
        keys[row] = (((ast[row] << 3) | alen[row]) << 10) | ((ost[row] << 3) | olen[row]);
    } else if (bid < 126) {
        // emb135h: bf16 of emb[:, :136] flattened to [4352][256]
        int rbase = (bid - 109) << 8;
        int b2 = rbase / LR, l2 = rbase - b2 * LR;
        for (int r = 0; r < 256; ++r) {
            embh[(size_t)(rbase + r) * 256 + tid] =
                __float2bfloat16(emb[((size_t)b2 * Ln + l2) * 256 + tid]);
            if (++l2 == LR) { l2 = 0; ++b2; }
        }
    }
}

// ---------------- merged projection: fp32 PQ (sign path) + bf16 MFMA PQ2 (agg path)
//                  + copy share ----------------
__global__ __launch_bounds__(256) void k_pq(const float* __restrict__ emb,
        const float* __restrict__ Wtrip,
        const __hip_bfloat16* __restrict__ embh, const __hip_bfloat16* __restrict__ WtGT,
        float* __restrict__ PQ, float* __restrict__ PQ2, float* __restrict__ out) {
    __shared__ float Als[32][68];
    __shared__ float Bls[32][64];
    int tid = threadIdx.x;
    int bid = blockIdx.x;
    copy_lin(emb, out, 1572864L + (long)bid * 2048, 2048, tid);

    if (bid < 544) {
        int m0 = (bid % 68) << 6;
        int j = bid / 68;
        const float* Bp = Wtrip + ((j < 4) ? (j << 6) : (65536 + ((j - 4) << 6)));
        int r0 = (tid & 15) << 2;
        int c0 = (tid >> 4) << 2;
        float acc[4][4] = {};
        for (int kk = 0; kk < 256; kk += 32) {
            __syncthreads();
            #pragma unroll
            for (int p = 0; p < 2; ++p) {
                int idx = tid + (p << 8);
                int row = idx >> 3;
                int kq = (idx & 7) << 2;
                int m = m0 + row;
                int b = m / LR;
                int l = m - b * LR;
                const float4 v = *(const float4*)(emb + (size_t)(b * Ln + l) * 256 + kk + kq);
                Als[kq + 0][row] = v.x; Als[kq + 1][row] = v.y;
                Als[kq + 2][row] = v.z; Als[kq + 3][row] = v.w;
            }
            #pragma unroll
            for (int p = 0; p < 2; ++p) {
                int idx = tid + (p << 8);
                int k = idx >> 4;
                int hq = (idx & 15) << 2;
                *(float4*)(&Bls[k][hq]) = *(const float4*)(Bp + (size_t)(kk + k) * 256 + hq);
            }
            __syncthreads();
            #pragma unroll
            for (int k = 0; k < 32; ++k) {
                float4 a  = *(const float4*)(&Als[k][r0]);
                float4 bv = *(const float4*)(&Bls[k][c0]);
                acc[0][0] += a.x*bv.x; acc[0][1] += a.x*bv.y; acc[0][2] += a.x*bv.z; acc[0][3] += a.x*bv.w;
                acc[1][0] += a.y*bv.x; acc[1][1] += a.y*bv.y; acc[1][2] += a.y*bv.z; acc[1][3] += a.y*bv.w;
                acc[2][0] += a.z*bv.x; acc[2][1] += a.z*bv.y; acc[2][2] += a.z*bv.z; acc[2][3] += a.z*bv.w;
                acc[3][0] += a.w*bv.x; acc[3][1] += a.w*bv.y; acc[3][2] += a.w*bv.z; acc[3][3] += a.w*bv.w;
            }
        }
        #pragma unroll
        for (int i = 0; i < 4; ++i)
            #pragma unroll
            for (int jj = 0; jj < 4; ++jj)
                PQ[(size_t)(m0 + r0 + i) * 512 + (j << 6) + c0 + jj] = acc[i][jj];
    } else {
        int bb = bid - 544;
        int wave = tid >> 6, lane = tid & 63;
        int m0 = ((bb % 68) << 6) + (wave << 4);
        int n0 = (bb / 68) << 6;
        int fr = lane & 15;
        int kq = (lane >> 4) << 3;
        f32x4 acc[4] = {};
        for (int k0 = 0; k0 < 256; k0 += 32) {
            bf16x8 a = *(const bf16x8*)(embh + (size_t)(m0 + fr) * 256 + k0 + kq);
            #pragma unroll
            for (int nf = 0; nf < 4; ++nf) {
                bf16x8 b = *(const bf16x8*)(WtGT + (size_t)(n0 + (nf << 4) + fr) * 256 + k0 + kq);
                acc[nf] = __builtin_amdgcn_mfma_f32_16x16x32_bf16(a, b, acc[nf], 0, 0, 0);
            }
        }
        int r0 = (lane >> 4) << 2;
        #pragma unroll
        for (int nf = 0; nf < 4; ++nf)
            #pragma unroll
            for (int r = 0; r < 4; ++r)
                PQ2[(size_t)(m0 + r0 + r) * 512 + n0 + (nf << 4) + fr] = acc[nf][r];
    }
}

// ---------------- combine: wave-per-row, XCD-swizzled (4 batches/XCD), no barriers
//                  + copy share ----------------
__global__ __launch_bounds__(256) void k_combine(const float* __restrict__ PQ,
        const float* __restrict__ PQ2,
        const float* __restrict__ Wtrip, const float* __restrict__ btrip,
        const int* __restrict__ sid,
        const int* __restrict__ ast, const int* __restrict__ alen,
        const int* __restrict__ ost, const int* __restrict__ olen,
        const float* __restrict__ Wattn, const float* __restrict__ W3g,
        const float* __restrict__ btg, const float* __restrict__ emb,
        float* __restrict__ out, float* __restrict__ node, float* __restrict__ nodeW,
        float* __restrict__ atg, float* __restrict__ asr) {
    int bid = blockIdx.x, tid = threadIdx.x;
    int wv = tid >> 6, lane = tid & 63;
    copy_lin(emb, out, 3801088L + (long)bid * 608, 608, tid);

    int s = ((bid & 7) << 9) | (bid >> 3);   // XCD swizzle: 4 batches per XCD
    int row = (s << 2) + wv;
    int b = row >> 9;
    int as_ = ast[row], al = alen[row];
    int os_ = ost[row], ol = olen[row];
    int c = lane << 2;
    const float* Pb  = PQ  + (size_t)b * LR * 512 + c;
    const float* Pb2 = PQ2 + (size_t)b * LR * 512 + c;

    f32x4 asum = {0.f,0.f,0.f,0.f}, osum = asum, p2 = asum, q2 = asum;
    for (int i = 0; i <= al; ++i) {
        size_t off = (size_t)(as_ + i) * 512;
        asum += *(const f32x4*)(Pb + off);
        p2   += *(const f32x4*)(Pb2 + off);
    }
    for (int i = 0; i <= ol; ++i) {
        size_t off = (size_t)(os_ + i) * 512 + 256;
        osum += *(const f32x4*)(Pb + off);
        q2   += *(const f32x4*)(Pb2 + off);
    }
    float ra = 1.f / (float)(al + 1), ro = 1.f / (float)(ol + 1);
    int sd = sid[row];

    f32x4 x = asum * ra + osum * ro
            + *(const f32x4*)(Wtrip + (size_t)(512 + sd) * 256 + c)
            + *(const f32x4*)(btrip + c);
    *(f32x4*)(node + (size_t)row * 256 + c) = x;

    f32x4 nw = p2 * ra + q2 * ro
             + *(const f32x4*)(W3g + sd * 256 + c)
             + *(const f32x4*)(btg + c);
    *(f32x4*)(nodeW + (size_t)row * 256 + c) = nw;

    f32x4 lx = leaky4(x);
    f32x4 w1 = *(const f32x4*)(Wattn + c);
    f32x4 w2 = *(const f32x4*)(Wattn + 256 + c);
    float s1 = lx.x*w1.x + lx.y*w1.y + lx.z*w1.z + lx.w*w1.w;
    float s2 = lx.x*w2.x + lx.y*w2.y + lx.z*w2.z + lx.w*w2.w;
    #pragma unroll
    for (int o = 32; o; o >>= 1) {
        s1 += __shfl_xor(s1, o);
        s2 += __shfl_xor(s2, o);
    }
    if (lane == 0) { atg[row] = s1; asr[row] = s2; }
}

// ---------------- edges: wave-per-target, XCD-swizzled, fused atomic scatter to out
//                  + copy share (rows>=128 of batches 24-31 only) ----------------
__global__ __launch_bounds__(256) void k_edges(
        const float* __restrict__ node, const float* __restrict__ nodeW,
        const float* __restrict__ atg, const float* __restrict__ asr,
        const float* __restrict__ ae, const float* __restrict__ battn,
        const float* __restrict__ ve, const float* __restrict__ bgat,
        const int* __restrict__ keys,
        const int* __restrict__ ast, const int* __restrict__ ost,
        const float* __restrict__ emb, float* __restrict__ out,
        int* __restrict__ bflag) {
    int bid = blockIdx.x;
    int tid = threadIdx.x;
    int wv = tid >> 6, lane = tid & 63;

    {   // copy: tails (rows>=128) of batches 24-31; disjoint from atomic targets (rows<128)
        const f32x4* s4 = (const f32x4*)emb;
        f32x4* d4 = (f32x4*)out;
        long base = ((24L + (bid >> 9)) << 18) + 8192 + (long)(bid & 511) * 496;
        for (int i = tid; i < 496; i += 256)
            d4[base + i] = s4[base + i];
    }

    int s = ((bid & 7) << 9) | (bid >> 3);   // XCD swizzle
    int tgt = (s << 2) + wv;
    int b = tgt >> 9, base = b << 9, lt = tgt & 511;

    int mykey = keys[tgt];
    int ka = mykey >> 10, ko = mykey & 1023;

    unsigned long long mA[8], mO[8];
    #pragma unroll
    for (int j = 0; j < 8; ++j) {
        int ls = (j << 6) + lane;
        int k2 = keys[base + ls];
        bool self = (ls == lt);
        mA[j] = __ballot(((k2 >> 10) == ka) && !self);
        mO[j] = __ballot(((k2 & 1023) == ko) && !self);
    }

    f32x4 xt4 = *(const f32x4*)(node + (size_t)tgt * 256 + (lane << 2));
    float a_t = atg[tgt];
    float ae0 = ae[0], ae1 = ae[1], b0 = battn[0];

    float s0a[8], s1a[8];
    unsigned long long mK[8];
    #pragma unroll
    for (int j = 0; j < 8; ++j) {
        s0a[j] = NEGSENT; s1a[j] = NEGSENT;
        unsigned long long m = mA[j] | mO[j];
        while (m) {
            int bit = __builtin_ctzll(m); m &= m - 1;
            int gs = base + (j << 6) + bit;
            f32x4 y = *(const f32x4*)(node + (size_t)gs * 256 + (lane << 2));
            float p = xt4.x * y.x + xt4.y * y.y + xt4.z * y.z + xt4.w * y.w;
            #pragma unroll
            for (int o = 32; o; o >>= 1) p += __shfl_xor(p, o);
            if (p > 0.f && lane == bit) {
                float bs = a_t + asr[gs] + b0;
                if ((mA[j] >> bit) & 1) s0a[j] = bs + ae0;
                if ((mO[j] >> bit) & 1) s1a[j] = bs + ae1;
            }
        }
        mK[j] = __ballot(s0a[j] > -1e29f || s1a[j] > -1e29f);
    }

    float mx = NEGSENT;
    #pragma unroll
    for (int j = 0; j < 8; ++j) mx = fmaxf(mx, fmaxf(s0a[j], s1a[j]));
    #pragma unroll
    for (int o = 32; o; o >>= 1) mx = fmaxf(mx, __shfl_xor(mx, o));
    bool has = mx > -1e29f;

    float se0 = 0.f, se1 = 0.f;
    #pragma unroll
    for (int j = 0; j < 8; ++j) {
        se0 += expf(s0a[j] - mx);
        se1 += expf(s1a[j] - mx);
    }
    #pragma unroll
    for (int o = 32; o; o >>= 1) { se0 += __shfl_xor(se0, o); se1 += __shfl_xor(se1, o); }
    float rden = 1.f / (se0 + se1);

    f32x4 res;
    if (has) {
        f32x4 agg4 = {0.f, 0.f, 0.f, 0.f};
        #pragma unroll
        for (int j = 0; j < 8; ++j) {
            unsigned long long m = mK[j];
            while (m) {
                int bit = __builtin_ctzll(m); m &= m - 1;
                int gs = base + (j << 6) + bit;
                float w0 = __shfl(s0a[j], bit);
                float w1 = __shfl(s1a[j], bit);
                float wt = (expf(w0 - mx) + expf(w1 - mx)) * rden;
                const f32x4 nw = *(const f32x4*)(nodeW + (size_t)gs * 256 + (lane << 2));
                agg4.x += wt * nw.x; agg4.y += wt * nw.y;
                agg4.z += wt * nw.z; agg4.w += wt * nw.w;
            }
        }
        f32x4 v1 = *(const f32x4*)(ve + (lane << 2));
        f32x4 v2 = *(const f32x4*)(ve + 256 + (lane << 2));
        f32x4 bg = *(const f32x4*)(bgat + (lane << 2));
        float c0 = se0 * rden, c1 = se1 * rden;
        res.x = fmaxf(agg4.x + c0 * v1.x + c1 * v2.x + bg.x, 0.f);
        res.y = fmaxf(agg4.y + c0 * v1.y + c1 * v2.y + bg.y, 0.f);
        res.z = fmaxf(agg4.z + c0 * v1.z + c1 * v2.z + bg.z, 0.f);
        res.w = fmaxf(agg4.w + c0 * v1.w + c1 * v2.w + bg.w, 0.f);
        if (lane == 0) bflag[b] = 1;
    } else {
        res = xt4;   // node fallback (corrected by k_fix iff batch has no edges at all)
    }
    int cen = (ast[tgt] + ost[tgt]) >> 1;
    float* orow = out + ((size_t)b * Ln + cen) * 256 + (lane << 2);
    atomicAdd(orow + 0, res.x);
    atomicAdd(orow + 1, res.y);
    atomicAdd(orow + 2, res.z);
    atomicAdd(orow + 3, res.w);
}

// ---------------- fix: batches with zero edges contributed node at centers -> subtract ----------------
__global__ __launch_bounds__(256) void k_fix(const float* __restrict__ node,
        const int* __restrict__ ast, const int* __restrict__ ost,
        const int* __restrict__ bflag, float* __restrict__ out) {
    int b = blockIdx.x;
    if (bflag[b]) return;
    int tid = threadIdx.x;
    for (int n = 0; n < 512; ++n) {
        int row = (b << 9) + n;
        int cen = (ast[row] + ost[row]) >> 1;
        atomicAdd(&out[((size_t)b * Ln + cen) * 256 + tid],
                  -node[(size_t)row * 256 + tid]);
    }
}

extern "C" void kernel_launch(void* const* d_in, const int* in_sizes, int n_in,
                              void* d_out, int out_size, void* d_ws, size_t ws_size,
                              hipStream_t stream) {
    const float* emb   = (const float*)d_in[0];
    const float* Wtrip = (const float*)d_in[1];
    const float* btrip = (const float*)d_in[2];
    const float* Eemb  = (const float*)d_in[3];
    const float* Wattn = (const float*)d_in[4];
    const float* battn = (const float*)d_in[5];
    const float* Wgat  = (const float*)d_in[6];
    const float* bgat  = (const float*)d_in[7];
    const int* ast  = (const int*)d_in[8];
    const int* alen = (const int*)d_in[9];
    const int* ost  = (const int*)d_in[10];
    const int* olen = (const int*)d_in[11];
    const int* sid  = (const int*)d_in[12];
    float* out = (float*)d_out;

    float* ws    = (float*)d_ws;
    float* PQ    = ws;                                    // [4352*512]
    float* PQ2   = PQ + (size_t)4352 * 512;               // [4352*512]
    float* node  = PQ2 + (size_t)4352 * 512;              // [ROWS*256]
    float* nodeW = node + (size_t)ROWS * 256;             // [ROWS*256]
    float* W3g   = nodeW + (size_t)ROWS * 256;            // [3*256]
    float* btg   = W3g + 768;                             // [256]
    float* atg   = btg + 256;                             // [ROWS]
    float* asr   = atg + ROWS;                            // [ROWS]
    float* ae    = asr + ROWS;                            // [2]
    float* ve    = ae + 2;                                // [512]
    int* bflag   = (int*)(ve + 512);                      // [Bn]
    int* keys    = bflag + Bn;                            // [ROWS]
    __hip_bfloat16* embh = (__hip_bfloat16*)(keys + ROWS + 32);   // [4352*256]
    __hip_bfloat16* WtGT = embh + (size_t)4352 * 256;             // [512*256]

    k_pre<<<1024, 256, 0, stream>>>(Wtrip, btrip, Eemb, Wattn, Wgat,
                                    ast, alen, ost, olen, emb, out,
                                    WtGT, embh, W3g, btg, ae, ve, keys, bflag);
    k_pq<<<1088, 256, 0, stream>>>(emb, Wtrip, embh, WtGT, PQ, PQ2, out);
    k_combine<<<ROWS / 4, 256, 0, stream>>>(PQ, PQ2, Wtrip, btrip, sid,
                                            ast, alen, ost, olen,
                                            Wattn, W3g, btg, emb, out, node, nodeW,
                                            atg, asr);
    k_edges<<<ROWS / 4, 256, 0, stream>>>(node, nodeW, atg, asr, ae, battn, ve, bgat,
                                          keys, ast, ost, emb, out, bflag);
    k_fix<<<Bn, 256, 0, stream>>>(node, ast, ost, bflag, out);
}

// Round 13
// 161.783 us; speedup vs baseline: 1.1064x; 1.1064x over previous
//
#include <hip/hip_runtime.h>
#include <math.h>

#define Bn 32
#define Ln 4096
#define ROWS 16384
#define LR 136
#define SLOPEC 0.2f
#define NEGSENT -1e30f

typedef __attribute__((ext_vector_type(4))) float f32x4;

__device__ __forceinline__ f32x4 leaky4(f32x4 v) {
    f32x4 r;
    r.x = v.x >= 0.f ? v.x : SLOPEC * v.x;
    r.y = v.y >= 0.f ? v.y : SLOPEC * v.y;
    r.z = v.z >= 0.f ? v.z : SLOPEC * v.z;
    r.w = v.w >= 0.f ? v.w : SLOPEC * v.w;
    return r;
}

// ---------------- dedicated full-buffer copy: 8,388,608 f32x4 slots ----------------
__global__ __launch_bounds__(256) void k_copy(const f32x4* __restrict__ s,
                                              f32x4* __restrict__ d) {
    long base = (long)blockIdx.x * 2048 + threadIdx.x;
    #pragma unroll
    for (int i = 0; i < 8; ++i)
        d[base + i * 256] = s[base + i * 256];
}

// ---------------- pre: WtG (fp32), W3g, btg, ae, ve, keys, bflag ----------------
__global__ __launch_bounds__(256) void k_pre(const float* __restrict__ Wtrip,
        const float* __restrict__ btrip, const float* __restrict__ Eemb,
        const float* __restrict__ Wattn, const float* __restrict__ Wgat,
        const int* __restrict__ ast, const int* __restrict__ alen,
        const int* __restrict__ ost, const int* __restrict__ olen,
        float* __restrict__ WtG, float* __restrict__ W3g, float* __restrict__ btg,
        float* __restrict__ ae, float* __restrict__ ve,
        int* __restrict__ keys, int* __restrict__ bflag) {
    int bid = blockIdx.x, tid = threadIdx.x;
    __shared__ float Als[32][68];
    __shared__ float Bls[32][64];
    __shared__ float red[4];
    __shared__ float vr0[8][32], vr1[8][32];
    if (bid < 32) {
        // WtG[mat] = Wtrip[mat*256:(mat+1)*256] @ Wgat[0:256]  (64x64 tile per block)
        int mat = bid >> 4, t = bid & 15;
        int m0 = (t >> 2) << 6, n0 = (t & 3) << 6;
        const float* A = Wtrip + mat * 65536;
        int r0 = (tid & 15) << 2, c0 = (tid >> 4) << 2;
        float acc[4][4] = {};
        for (int kk = 0; kk < 256; kk += 32) {
            __syncthreads();
            #pragma unroll
            for (int p = 0; p < 2; ++p) {
                int idx = tid + (p << 8);
                int row = idx >> 3, kq = (idx & 7) << 2;
                const float4 v = *(const float4*)(A + (size_t)(m0 + row) * 256 + kk + kq);
                Als[kq + 0][row] = v.x; Als[kq + 1][row] = v.y;
                Als[kq + 2][row] = v.z; Als[kq + 3][row] = v.w;
            }
            #pragma unroll
            for (int p = 0; p < 2; ++p) {
                int idx = tid + (p << 8);
                int k = idx >> 4, hq = (idx & 15) << 2;
                *(float4*)(&Bls[k][hq]) = *(const float4*)(Wgat + (size_t)(kk + k) * 256 + n0 + hq);
            }
            __syncthreads();
            #pragma unroll
            for (int k = 0; k < 32; ++k) {
                float4 a  = *(const float4*)(&Als[k][r0]);
                float4 bv = *(const float4*)(&Bls[k][c0]);
                acc[0][0] += a.x*bv.x; acc[0][1] += a.x*bv.y; acc[0][2] += a.x*bv.z; acc[0][3] += a.x*bv.w;
                acc[1][0] += a.y*bv.x; acc[1][1] += a.y*bv.y; acc[1][2] += a.y*bv.z; acc[1][3] += a.y*bv.w;
                acc[2][0] += a.z*bv.x; acc[2][1] += a.z*bv.y; acc[2][2] += a.z*bv.z; acc[2][3] += a.z*bv.w;
                acc[3][0] += a.w*bv.x; acc[3][1] += a.w*bv.y; acc[3][2] += a.w*bv.z; acc[3][3] += a.w*bv.w;
            }
        }
        #pragma unroll
        for (int i = 0; i < 4; ++i)
            #pragma unroll
            for (int j = 0; j < 4; ++j)
                WtG[mat * 65536 + (size_t)(m0 + r0 + i) * 256 + n0 + c0 + j] = acc[i][j];
    } else if (bid == 32) {
        float s = 0.f;
        for (int k = 0; k < 256; ++k) s += btrip[k] * Wgat[(size_t)k * 256 + tid];
        btg[tid] = s;
    } else if (bid == 33) {
        if (tid < Bn) bflag[tid] = 0;
        #pragma unroll
        for (int e = 0; e < 2; ++e) {
            float x = Eemb[e * 256 + tid];
            float lx = x >= 0.f ? x : SLOPEC * x;
            float s = lx * Wattn[512 + tid];
            #pragma unroll
            for (int o = 32; o; o >>= 1) s += __shfl_down(s, o);
            if ((tid & 63) == 0) red[tid >> 6] = s;
            __syncthreads();
            if (tid == 0) ae[e] = red[0] + red[1] + red[2] + red[3];
            __syncthreads();
        }
    } else if (bid < 37) {
        int s = bid - 34;
        float acc = 0.f;
        for (int k = 0; k < 256; ++k)
            acc += Wtrip[(size_t)(512 + s) * 256 + k] * Wgat[(size_t)k * 256 + tid];
        W3g[s * 256 + tid] = acc;
    } else if (bid < 45) {
        int j = bid - 37;
        int n0 = j << 5;
        int nl = tid & 31, kg = tid >> 5;
        float p0 = 0.f, p1 = 0.f;
        for (int kk = 0; kk < 32; ++kk) {
            int k = (kg << 5) + kk;
            float w = Wgat[(size_t)(256 + k) * 256 + n0 + nl];
            p0 += Eemb[k] * w;
            p1 += Eemb[256 + k] * w;
        }
        vr0[kg][nl] = p0; vr1[kg][nl] = p1;
        __syncthreads();
        if (tid < 32) {
            float s0 = 0.f, s1 = 0.f;
            #pragma unroll
            for (int g = 0; g < 8; ++g) { s0 += vr0[g][tid]; s1 += vr1[g][tid]; }
            ve[n0 + tid] = s0;
            ve[256 + n0 + tid] = s1;
        }
    } else if (bid < 109) {
        int row = (bid - 45) * 256 + tid;
        keys[row] = (((ast[row] << 3) | alen[row]) << 10) | ((ost[row] << 3) | olen[row]);
    }
}

// ---------------- PQ = emb[:, :136] @ [Wtop | Wbot | WtopG | WbotG]  (M=4352,K=256,N=1024) ----------------
__global__ __launch_bounds__(256) void k_pq(const float* __restrict__ emb,
        const float* __restrict__ Wtrip, const float* __restrict__ WtG,
        float* __restrict__ PQ) {
    __shared__ float Als[32][68];
    __shared__ float Bls[32][64];
    int tid = threadIdx.x;
    int m0 = blockIdx.x << 6;
    int j = blockIdx.y;   // n-tile 0..15
    const float* Bp;
    if (j < 4)       Bp = Wtrip + (j << 6);
    else if (j < 8)  Bp = Wtrip + 65536 + ((j - 4) << 6);
    else if (j < 12) Bp = WtG + ((j - 8) << 6);
    else             Bp = WtG + 65536 + ((j - 12) << 6);
    int r0 = (tid & 15) << 2;
    int c0 = (tid >> 4) << 2;
    float acc[4][4] = {};
    for (int kk = 0; kk < 256; kk += 32) {
        __syncthreads();
        #pragma unroll
        for (int p = 0; p < 2; ++p) {   // A: 64 rows x 32 k (k-major LDS)
            int idx = tid + (p << 8);
            int row = idx >> 3;
            int kq = (idx & 7) << 2;
            int m = m0 + row;
            int b = m / LR;
            int l = m - b * LR;
            const float4 v = *(const float4*)(emb + (size_t)(b * Ln + l) * 256 + kk + kq);
            Als[kq + 0][row] = v.x; Als[kq + 1][row] = v.y;
            Als[kq + 2][row] = v.z; Als[kq + 3][row] = v.w;
        }
        #pragma unroll
        for (int p = 0; p < 2; ++p) {   // B: 32 k x 64 cols
            int idx = tid + (p << 8);
            int k = idx >> 4;
            int hq = (idx & 15) << 2;
            *(float4*)(&Bls[k][hq]) = *(const float4*)(Bp + (size_t)(kk + k) * 256 + hq);
        }
        __syncthreads();
        #pragma unroll
        for (int k = 0; k < 32; ++k) {
            float4 a  = *(const float4*)(&Als[k][r0]);
            float4 bv = *(const float4*)(&Bls[k][c0]);
            acc[0][0] += a.x*bv.x; acc[0][1] += a.x*bv.y; acc[0][2] += a.x*bv.z; acc[0][3] += a.x*bv.w;
            acc[1][0] += a.y*bv.x; acc[1][1] += a.y*bv.y; acc[1][2] += a.y*bv.z; acc[1][3] += a.y*bv.w;
            acc[2][0] += a.z*bv.x; acc[2][1] += a.z*bv.y; acc[2][2] += a.z*bv.z; acc[2][3] += a.z*bv.w;
            acc[3][0] += a.w*bv.x; acc[3][1] += a.w*bv.y; acc[3][2] += a.w*bv.z; acc[3][3] += a.w*bv.w;
        }
    }
    #pragma unroll
    for (int i = 0; i < 4; ++i)
        #pragma unroll
        for (int jj = 0; jj < 4; ++jj)
            PQ[(size_t)(m0 + r0 + i) * 1024 + (j << 6) + c0 + jj] = acc[i][jj];
}

// ---------------- combine: wave-per-row, no barriers -> node, nodeW, atg, asr ----------------
__global__ __launch_bounds__(256) void k_combine(const float* __restrict__ PQ,
        const float* __restrict__ Wtrip, const float* __restrict__ btrip,
        const int* __restrict__ sid,
        const int* __restrict__ ast, const int* __restrict__ alen,
        const int* __restrict__ ost, const int* __restrict__ olen,
        const float* __restrict__ Wattn, const float* __restrict__ W3g,
        const float* __restrict__ btg,
        float* __restrict__ node, float* __restrict__ nodeW,
        float* __restrict__ atg, float* __restrict__ asr) {
    int bid = blockIdx.x, tid = threadIdx.x;
    int wv = tid >> 6, lane = tid & 63;

    int row = (bid << 2) + wv;
    int b = row >> 9;
    int as_ = ast[row], al = alen[row];
    int os_ = ost[row], ol = olen[row];
    int c = lane << 2;
    const float* Pb = PQ + (size_t)b * LR * 1024 + c;

    f32x4 asum = {0.f,0.f,0.f,0.f}, osum = asum, p2 = asum, q2 = asum;
    for (int i = 0; i <= al; ++i) {
        const float* rp = Pb + (size_t)(as_ + i) * 1024;
        asum += *(const f32x4*)rp;
        p2   += *(const f32x4*)(rp + 512);
    }
    for (int i = 0; i <= ol; ++i) {
        const float* rp = Pb + (size_t)(os_ + i) * 1024 + 256;
        osum += *(const f32x4*)rp;
        q2   += *(const f32x4*)(rp + 512);
    }
    float ra = 1.f / (float)(al + 1), ro = 1.f / (float)(ol + 1);
    int sd = sid[row];

    f32x4 x = asum * ra + osum * ro
            + *(const f32x4*)(Wtrip + (size_t)(512 + sd) * 256 + c)
            + *(const f32x4*)(btrip + c);
    *(f32x4*)(node + (size_t)row * 256 + c) = x;

    f32x4 nw = p2 * ra + q2 * ro
             + *(const f32x4*)(W3g + sd * 256 + c)
             + *(const f32x4*)(btg + c);
    *(f32x4*)(nodeW + (size_t)row * 256 + c) = nw;

    f32x4 lx = leaky4(x);
    f32x4 w1 = *(const f32x4*)(Wattn + c);
    f32x4 w2 = *(const f32x4*)(Wattn + 256 + c);
    float s1 = lx.x*w1.x + lx.y*w1.y + lx.z*w1.z + lx.w*w1.w;
    float s2 = lx.x*w2.x + lx.y*w2.y + lx.z*w2.z + lx.w*w2.w;
    #pragma unroll
    for (int o = 32; o; o >>= 1) {
        s1 += __shfl_xor(s1, o);
        s2 += __shfl_xor(s2, o);
    }
    if (lane == 0) { atg[row] = s1; asr[row] = s2; }
}

// ---------------- sparse edges: wave-per-target, zero barriers, all-register ----------------
__global__ __launch_bounds__(256) void k_edges(
        const float* __restrict__ node, const float* __restrict__ nodeW,
        const float* __restrict__ atg, const float* __restrict__ asr,
        const float* __restrict__ ae, const float* __restrict__ battn,
        const float* __restrict__ ve, const float* __restrict__ bgat,
        const int* __restrict__ keys,
        float* __restrict__ nadd, int* __restrict__ bflag) {
    int bid = blockIdx.x;
    int tid = threadIdx.x;
    int wv = tid >> 6, lane = tid & 63;

    int tgt = (bid << 2) + wv;
    int b = tgt >> 9, base = b << 9, lt = tgt & 511;

    int mykey = keys[tgt];
    int ka = mykey >> 10, ko = mykey & 1023;

    unsigned long long mA[8], mO[8];
    #pragma unroll
    for (int j = 0; j < 8; ++j) {
        int ls = (j << 6) + lane;
        int k2 = keys[base + ls];
        bool self = (ls == lt);
        mA[j] = __ballot(((k2 >> 10) == ka) && !self);
        mO[j] = __ballot(((k2 & 1023) == ko) && !self);
    }

    f32x4 xt4 = *(const f32x4*)(node + (size_t)tgt * 256 + (lane << 2));
    float a_t = atg[tgt];
    float ae0 = ae[0], ae1 = ae[1], b0 = battn[0];

    float s0a[8], s1a[8];
    unsigned long long mK[8];
    #pragma unroll
    for (int j = 0; j < 8; ++j) {
        s0a[j] = NEGSENT; s1a[j] = NEGSENT;
        unsigned long long m = mA[j] | mO[j];
        while (m) {
            int bit = __builtin_ctzll(m); m &= m - 1;
            int gs = base + (j << 6) + bit;
            f32x4 y = *(const f32x4*)(node + (size_t)gs * 256 + (lane << 2));
            float p = xt4.x * y.x + xt4.y * y.y + xt4.z * y.z + xt4.w * y.w;
            #pragma unroll
            for (int o = 32; o; o >>= 1) p += __shfl_xor(p, o);
            if (p > 0.f && lane == bit) {
                float bs = a_t + asr[gs] + b0;
                if ((mA[j] >> bit) & 1) s0a[j] = bs + ae0;
                if ((mO[j] >> bit) & 1) s1a[j] = bs + ae1;
            }
        }
        mK[j] = __ballot(s0a[j] > -1e29f || s1a[j] > -1e29f);
    }

    float mx = NEGSENT;
    #pragma unroll
    for (int j = 0; j < 8; ++j) mx = fmaxf(mx, fmaxf(s0a[j], s1a[j]));
    #pragma unroll
    for (int o = 32; o; o >>= 1) mx = fmaxf(mx, __shfl_xor(mx, o));
    bool has = mx > -1e29f;

    float se0 = 0.f, se1 = 0.f;
    #pragma unroll
    for (int j = 0; j < 8; ++j) {
        se0 += expf(s0a[j] - mx);
        se1 += expf(s1a[j] - mx);
    }
    #pragma unroll
    for (int o = 32; o; o >>= 1) { se0 += __shfl_xor(se0, o); se1 += __shfl_xor(se1, o); }
    float rden = 1.f / (se0 + se1);

    f32x4 res;
    if (has) {
        f32x4 agg4 = {0.f, 0.f, 0.f, 0.f};
        #pragma unroll
        for (int j = 0; j < 8; ++j) {
            unsigned long long m = mK[j];
            while (m) {
                int bit = __builtin_ctzll(m); m &= m - 1;
                int gs = base + (j << 6) + bit;
                float w0 = __shfl(s0a[j], bit);
                float w1 = __shfl(s1a[j], bit);
                float wt = (expf(w0 - mx) + expf(w1 - mx)) * rden;
                const f32x4 nw = *(const f32x4*)(nodeW + (size_t)gs * 256 + (lane << 2));
                agg4.x += wt * nw.x; agg4.y += wt * nw.y;
                agg4.z += wt * nw.z; agg4.w += wt * nw.w;
            }
        }
        f32x4 v1 = *(const f32x4*)(ve + (lane << 2));
        f32x4 v2 = *(const f32x4*)(ve + 256 + (lane << 2));
        f32x4 bg = *(const f32x4*)(bgat + (lane << 2));
        float c0 = se0 * rden, c1 = se1 * rden;
        res.x = fmaxf(agg4.x + c0 * v1.x + c1 * v2.x + bg.x, 0.f);
        res.y = fmaxf(agg4.y + c0 * v1.y + c1 * v2.y + bg.y, 0.f);
        res.z = fmaxf(agg4.z + c0 * v1.z + c1 * v2.z + bg.z, 0.f);
        res.w = fmaxf(agg4.w + c0 * v1.w + c1 * v2.w + bg.w, 0.f);
        if (lane == 0) bflag[b] = 1;
    } else {
        res = xt4;
    }
    *(f32x4*)(nadd + (size_t)tgt * 256 + (lane << 2)) = res;
}

// ---------------- scatter (RMW on out): rows<128 already hold emb from k_copy ----------------
__global__ __launch_bounds__(256) void k_scatter(const float* __restrict__ nadd,
        const int* __restrict__ ast, const int* __restrict__ ost,
        const int* __restrict__ bflag, float* __restrict__ out) {
    int b = blockIdx.x >> 7;
    if (!bflag[b]) return;
    int r = blockIdx.x & 127;
    int tid = threadIdx.x;

    __shared__ int cen[512];
    __shared__ unsigned long long s_mask[8];
    for (int n = tid; n < 512; n += 256)
        cen[n] = (ast[(b << 9) + n] + ost[(b << 9) + n]) >> 1;
    __syncthreads();
    #pragma unroll
    for (int p = 0; p < 2; ++p) {
        int n = tid + (p << 8);
        unsigned long long bal = __ballot(cen[n] == r);
        if ((tid & 63) == 0) s_mask[(p << 2) + (tid >> 6)] = bal;
    }
    __syncthreads();
    unsigned long long any = s_mask[0] | s_mask[1] | s_mask[2] | s_mask[3]
                           | s_mask[4] | s_mask[5] | s_mask[6] | s_mask[7];
    if (!any) return;
    size_t o = ((size_t)b * Ln + r) * 256 + tid;
    float acc = out[o];
    for (int w = 0; w < 8; ++w) {
        unsigned long long m = s_mask[w];
        while (m) {
            int n = (w << 6) + __builtin_ctzll(m); m &= m - 1;
            acc += nadd[((size_t)(b << 9) + n) * 256 + tid];
        }
    }
    out[o] = acc;
}

extern "C" void kernel_launch(void* const* d_in, const int* in_sizes, int n_in,
                              void* d_out, int out_size, void* d_ws, size_t ws_size,
                              hipStream_t stream) {
    const float* emb   = (const float*)d_in[0];
    const float* Wtrip = (const float*)d_in[1];
    const float* btrip = (const float*)d_in[2];
    const float* Eemb  = (const float*)d_in[3];
    const float* Wattn = (const float*)d_in[4];
    const float* battn = (const float*)d_in[5];
    const float* Wgat  = (const float*)d_in[6];
    const float* bgat  = (const float*)d_in[7];
    const int* ast  = (const int*)d_in[8];
    const int* alen = (const int*)d_in[9];
    const int* ost  = (const int*)d_in[10];
    const int* olen = (const int*)d_in[11];
    const int* sid  = (const int*)d_in[12];
    float* out = (float*)d_out;

    float* ws    = (float*)d_ws;
    float* PQ    = ws;                                    // [4352*1024] 17.8 MB
    float* node  = PQ + (size_t)4352 * 1024;              // [ROWS*256]
    float* nodeW = node + (size_t)ROWS * 256;             // [ROWS*256]
    float* nadd  = nodeW + (size_t)ROWS * 256;            // [ROWS*256]
    float* WtG   = nadd + (size_t)ROWS * 256;             // [2*256*256]
    float* W3g   = WtG + 2 * 65536;                       // [3*256]
    float* btg   = W3g + 768;                             // [256]
    float* atg   = btg + 256;                             // [ROWS]
    float* asr   = atg + ROWS;                            // [ROWS]
    float* ae    = asr + ROWS;                            // [2]
    float* ve    = ae + 2;                                // [512]
    int* bflag   = (int*)(ve + 512);                      // [Bn]
    int* keys    = bflag + Bn;                            // [ROWS]

    k_copy<<<4096, 256, 0, stream>>>((const f32x4*)emb, (f32x4*)out);
    k_pre<<<109, 256, 0, stream>>>(Wtrip, btrip, Eemb, Wattn, Wgat,
                                   ast, alen, ost, olen,
                                   WtG, W3g, btg, ae, ve, keys, bflag);
    k_pq<<<dim3(68, 16), 256, 0, stream>>>(emb, Wtrip, WtG, PQ);
    k_combine<<<ROWS / 4, 256, 0, stream>>>(PQ, Wtrip, btrip, sid,
                                            ast, alen, ost, olen,
                                            Wattn, W3g, btg, node, nodeW,
                                            atg, asr);
    k_edges<<<ROWS / 4, 256, 0, stream>>>(node, nodeW, atg, asr, ae, battn, ve, bgat,
                                          keys, nadd, bflag);
    k_scatter<<<Bn * 128, 256, 0, stream>>>(nadd, ast, ost, bflag, out);
}

// Round 14
// 146.381 us; speedup vs baseline: 1.2228x; 1.1052x over previous
//
#include <hip/hip_runtime.h>
#include <math.h>

#define Bn 32
#define Ln 4096
#define ROWS 16384
#define LR 136
#define SLOPEC 0.2f
#define NEGSENT -1e30f
// Linear full-buffer copy: 8,388,608 f32x4 slots.
// k_pre [0, 2097152) | k_pq [2097152, 3211264) | k_combine [3211264, 6356992)
// k_edges [6356992, 8388608). Rows<128 overwritten by k_scatter.

typedef __attribute__((ext_vector_type(4))) float f32x4;

__device__ __forceinline__ void copy_lin(const float* __restrict__ emb,
        float* __restrict__ out, long start, int count, int tid) {
    const f32x4* s4 = (const f32x4*)emb;
    f32x4* d4 = (f32x4*)out;
    for (int i = tid; i < count; i += 256)
        d4[start + i] = s4[start + i];
}

__device__ __forceinline__ f32x4 leaky4(f32x4 v) {
    f32x4 r;
    r.x = v.x >= 0.f ? v.x : SLOPEC * v.x;
    r.y = v.y >= 0.f ? v.y : SLOPEC * v.y;
    r.z = v.z >= 0.f ? v.z : SLOPEC * v.z;
    r.w = v.w >= 0.f ? v.w : SLOPEC * v.w;
    return r;
}

// ---------------- pre: WtG, W3g, btg, ae, ve, keys, bflag + copy share ----------------
__global__ __launch_bounds__(256) void k_pre(const float* __restrict__ Wtrip,
        const float* __restrict__ btrip, const float* __restrict__ Eemb,
        const float* __restrict__ Wattn, const float* __restrict__ Wgat,
        const int* __restrict__ ast, const int* __restrict__ alen,
        const int* __restrict__ ost, const int* __restrict__ olen,
        const float* __restrict__ emb, float* __restrict__ out,
        float* __restrict__ WtG, float* __restrict__ W3g, float* __restrict__ btg,
        float* __restrict__ ae, float* __restrict__ ve,
        int* __restrict__ keys, int* __restrict__ bflag) {
    int bid = blockIdx.x, tid = threadIdx.x;
    copy_lin(emb, out, (long)bid * 2048, 2048, tid);
    __shared__ float Als[32][68];
    __shared__ float Bls[32][64];
    __shared__ float red[4];
    __shared__ float vr0[8][32], vr1[8][32];
    if (bid < 32) {
        int mat = bid >> 4, t = bid & 15;
        int m0 = (t >> 2) << 6, n0 = (t & 3) << 6;
        const float* A = Wtrip + mat * 65536;
        int r0 = (tid & 15) << 2, c0 = (tid >> 4) << 2;
        float acc[4][4] = {};
        for (int kk = 0; kk < 256; kk += 32) {
            __syncthreads();
            #pragma unroll
            for (int p = 0; p < 2; ++p) {
                int idx = tid + (p << 8);
                int row = idx >> 3, kq = (idx & 7) << 2;
                const float4 v = *(const float4*)(A + (size_t)(m0 + row) * 256 + kk + kq);
                Als[kq + 0][row] = v.x; Als[kq + 1][row] = v.y;
                Als[kq + 2][row] = v.z; Als[kq + 3][row] = v.w;
            }
            #pragma unroll
            for (int p = 0; p < 2; ++p) {
                int idx = tid + (p << 8);
                int k = idx >> 4, hq = (idx & 15) << 2;
                *(float4*)(&Bls[k][hq]) = *(const float4*)(Wgat + (size_t)(kk + k) * 256 + n0 + hq);
            }
            __syncthreads();
            #pragma unroll
            for (int k = 0; k < 32; ++k) {
                float4 a  = *(const float4*)(&Als[k][r0]);
                float4 bv = *(const float4*)(&Bls[k][c0]);
                acc[0][0] += a.x*bv.x; acc[0][1] += a.x*bv.y; acc[0][2] += a.x*bv.z; acc[0][3] += a.x*bv.w;
                acc[1][0] += a.y*bv.x; acc[1][1] += a.y*bv.y; acc[1][2] += a.y*bv.z; acc[1][3] += a.y*bv.w;
                acc[2][0] += a.z*bv.x; acc[2][1] += a.z*bv.y; acc[2][2] += a.z*bv.z; acc[2][3] += a.z*bv.w;
                acc[3][0] += a.w*bv.x; acc[3][1] += a.w*bv.y; acc[3][2] += a.w*bv.z; acc[3][3] += a.w*bv.w;
            }
        }
        #pragma unroll
        for (int i = 0; i < 4; ++i)
            #pragma unroll
            for (int j = 0; j < 4; ++j)
                WtG[mat * 65536 + (size_t)(m0 + r0 + i) * 256 + n0 + c0 + j] = acc[i][j];
    } else if (bid == 32) {
        float s = 0.f;
        for (int k = 0; k < 256; ++k) s += btrip[k] * Wgat[(size_t)k * 256 + tid];
        btg[tid] = s;
    } else if (bid == 33) {
        if (tid < Bn) bflag[tid] = 0;
        #pragma unroll
        for (int e = 0; e < 2; ++e) {
            float x = Eemb[e * 256 + tid];
            float lx = x >= 0.f ? x : SLOPEC * x;
            float s = lx * Wattn[512 + tid];
            #pragma unroll
            for (int o = 32; o; o >>= 1) s += __shfl_down(s, o);
            if ((tid & 63) == 0) red[tid >> 6] = s;
            __syncthreads();
            if (tid == 0) ae[e] = red[0] + red[1] + red[2] + red[3];
            __syncthreads();
        }
    } else if (bid < 37) {
        int s = bid - 34;
        float acc = 0.f;
        for (int k = 0; k < 256; ++k)
            acc += Wtrip[(size_t)(512 + s) * 256 + k] * Wgat[(size_t)k * 256 + tid];
        W3g[s * 256 + tid] = acc;
    } else if (bid < 45) {
        int j = bid - 37;
        int n0 = j << 5;
        int nl = tid & 31, kg = tid >> 5;
        float p0 = 0.f, p1 = 0.f;
        for (int kk = 0; kk < 32; ++kk) {
            int k = (kg << 5) + kk;
            float w = Wgat[(size_t)(256 + k) * 256 + n0 + nl];
            p0 += Eemb[k] * w;
            p1 += Eemb[256 + k] * w;
        }
        vr0[kg][nl] = p0; vr1[kg][nl] = p1;
        __syncthreads();
        if (tid < 32) {
            float s0 = 0.f, s1 = 0.f;
            #pragma unroll
            for (int g = 0; g < 8; ++g) { s0 += vr0[g][tid]; s1 += vr1[g][tid]; }
            ve[n0 + tid] = s0;
            ve[256 + n0 + tid] = s1;
        }
    } else if (bid < 109) {
        int row = (bid - 45) * 256 + tid;
        keys[row] = (((ast[row] << 3) | alen[row]) << 10) | ((ost[row] << 3) | olen[row]);
    }
}

// ---------------- PQ = emb[:, :136] @ [Wtop | Wbot | WtopG | WbotG]  (M=4352,K=256,N=1024)
//                  + copy share ----------------
__global__ __launch_bounds__(256) void k_pq(const float* __restrict__ emb,
        const float* __restrict__ Wtrip, const float* __restrict__ WtG,
        float* __restrict__ PQ, float* __restrict__ out) {
    __shared__ float Als[32][68];
    __shared__ float Bls[32][64];
    int tid = threadIdx.x;
    {
        int bid = blockIdx.y * 68 + blockIdx.x;   // 1088 blocks x 1024 slots
        copy_lin(emb, out, 2097152L + (long)bid * 1024, 1024, tid);
    }
    int m0 = blockIdx.x << 6;
    int j = blockIdx.y;   // n-tile 0..15
    const float* Bp;
    if (j < 4)       Bp = Wtrip + (j << 6);
    else if (j < 8)  Bp = Wtrip + 65536 + ((j - 4) << 6);
    else if (j < 12) Bp = WtG + ((j - 8) << 6);
    else             Bp = WtG + 65536 + ((j - 12) << 6);
    int r0 = (tid & 15) << 2;
    int c0 = (tid >> 4) << 2;
    float acc[4][4] = {};
    for (int kk = 0; kk < 256; kk += 32) {
        __syncthreads();
        #pragma unroll
        for (int p = 0; p < 2; ++p) {   // A: 64 rows x 32 k (k-major LDS)
            int idx = tid + (p << 8);
            int row = idx >> 3;
            int kq = (idx & 7) << 2;
            int m = m0 + row;
            int b = m / LR;
            int l = m - b * LR;
            const float4 v = *(const float4*)(emb + (size_t)(b * Ln + l) * 256 + kk + kq);
            Als[kq + 0][row] = v.x; Als[kq + 1][row] = v.y;
            Als[kq + 2][row] = v.z; Als[kq + 3][row] = v.w;
        }
        #pragma unroll
        for (int p = 0; p < 2; ++p) {   // B: 32 k x 64 cols
            int idx = tid + (p << 8);
            int k = idx >> 4;
            int hq = (idx & 15) << 2;
            *(float4*)(&Bls[k][hq]) = *(const float4*)(Bp + (size_t)(kk + k) * 256 + hq);
        }
        __syncthreads();
        #pragma unroll
        for (int k = 0; k < 32; ++k) {
            float4 a  = *(const float4*)(&Als[k][r0]);
            float4 bv = *(const float4*)(&Bls[k][c0]);
            acc[0][0] += a.x*bv.x; acc[0][1] += a.x*bv.y; acc[0][2] += a.x*bv.z; acc[0][3] += a.x*bv.w;
            acc[1][0] += a.y*bv.x; acc[1][1] += a.y*bv.y; acc[1][2] += a.y*bv.z; acc[1][3] += a.y*bv.w;
            acc[2][0] += a.z*bv.x; acc[2][1] += a.z*bv.y; acc[2][2] += a.z*bv.z; acc[2][3] += a.z*bv.w;
            acc[3][0] += a.w*bv.x; acc[3][1] += a.w*bv.y; acc[3][2] += a.w*bv.z; acc[3][3] += a.w*bv.w;
        }
    }
    #pragma unroll
    for (int i = 0; i < 4; ++i)
        #pragma unroll
        for (int jj = 0; jj < 4; ++jj)
            PQ[(size_t)(m0 + r0 + i) * 1024 + (j << 6) + c0 + jj] = acc[i][jj];
}

// ---------------- combine: wave-per-row, XCD-swizzled (4 batches/XCD), no barriers
//                  + copy share (linear by bid) ----------------
__global__ __launch_bounds__(256) void k_combine(const float* __restrict__ PQ,
        const float* __restrict__ Wtrip, const float* __restrict__ btrip,
        const int* __restrict__ sid,
        const int* __restrict__ ast, const int* __restrict__ alen,
        const int* __restrict__ ost, const int* __restrict__ olen,
        const float* __restrict__ Wattn, const float* __restrict__ W3g,
        const float* __restrict__ btg, const float* __restrict__ emb,
        float* __restrict__ out, float* __restrict__ node, float* __restrict__ nodeW,
        float* __restrict__ atg, float* __restrict__ asr) {
    int bid = blockIdx.x, tid = threadIdx.x;
    int wv = tid >> 6, lane = tid & 63;
    copy_lin(emb, out, 3211264L + (long)bid * 768, 768, tid);

    int s = ((bid & 7) << 9) | (bid >> 3);   // XCD swizzle: 4 whole batches per XCD
    int row = (s << 2) + wv;
    int b = row >> 9;
    int as_ = ast[row], al = alen[row];
    int os_ = ost[row], ol = olen[row];
    int c = lane << 2;
    const float* Pb = PQ + (size_t)b * LR * 1024 + c;

    f32x4 asum = {0.f,0.f,0.f,0.f}, osum = asum, p2 = asum, q2 = asum;
    for (int i = 0; i <= al; ++i) {
        const float* rp = Pb + (size_t)(as_ + i) * 1024;
        asum += *(const f32x4*)rp;
        p2   += *(const f32x4*)(rp + 512);
    }
    for (int i = 0; i <= ol; ++i) {
        const float* rp = Pb + (size_t)(os_ + i) * 1024 + 256;
        osum += *(const f32x4*)rp;
        q2   += *(const f32x4*)(rp + 512);
    }
    float ra = 1.f / (float)(al + 1), ro = 1.f / (float)(ol + 1);
    int sd = sid[row];

    f32x4 x = asum * ra + osum * ro
            + *(const f32x4*)(Wtrip + (size_t)(512 + sd) * 256 + c)
            + *(const f32x4*)(btrip + c);
    *(f32x4*)(node + (size_t)row * 256 + c) = x;

    f32x4 nw = p2 * ra + q2 * ro
             + *(const f32x4*)(W3g + sd * 256 + c)
             + *(const f32x4*)(btg + c);
    *(f32x4*)(nodeW + (size_t)row * 256 + c) = nw;

    f32x4 lx = leaky4(x);
    f32x4 w1 = *(const f32x4*)(Wattn + c);
    f32x4 w2 = *(const f32x4*)(Wattn + 256 + c);
    float s1 = lx.x*w1.x + lx.y*w1.y + lx.z*w1.z + lx.w*w1.w;
    float s2 = lx.x*w2.x + lx.y*w2.y + lx.z*w2.z + lx.w*w2.w;
    #pragma unroll
    for (int o = 32; o; o >>= 1) {
        s1 += __shfl_xor(s1, o);
        s2 += __shfl_xor(s2, o);
    }
    if (lane == 0) { atg[row] = s1; asr[row] = s2; }
}

// ---------------- sparse edges: wave-per-target, XCD-swizzled, zero barriers
//                  + copy share (linear by bid) ----------------
__global__ __launch_bounds__(256) void k_edges(
        const float* __restrict__ node, const float* __restrict__ nodeW,
        const float* __restrict__ atg, const float* __restrict__ asr,
        const float* __restrict__ ae, const float* __restrict__ battn,
        const float* __restrict__ ve, const float* __restrict__ bgat,
        const int* __restrict__ keys,
        const float* __restrict__ emb, float* __restrict__ out,
        float* __restrict__ nadd, int* __restrict__ bflag) {
    int bid = blockIdx.x;
    int tid = threadIdx.x;
    int wv = tid >> 6, lane = tid & 63;

    copy_lin(emb, out, 6356992L + (long)bid * 496, 496, tid);

    int s = ((bid & 7) << 9) | (bid >> 3);   // XCD swizzle: 4 whole batches per XCD
    int tgt = (s << 2) + wv;
    int b = tgt >> 9, base = b << 9, lt = tgt & 511;

    int mykey = keys[tgt];
    int ka = mykey >> 10, ko = mykey & 1023;

    unsigned long long mA[8], mO[8];
    #pragma unroll
    for (int j = 0; j < 8; ++j) {
        int ls = (j << 6) + lane;
        int k2 = keys[base + ls];
        bool self = (ls == lt);
        mA[j] = __ballot(((k2 >> 10) == ka) && !self);
        mO[j] = __ballot(((k2 & 1023) == ko) && !self);
    }

    f32x4 xt4 = *(const f32x4*)(node + (size_t)tgt * 256 + (lane << 2));
    float a_t = atg[tgt];
    float ae0 = ae[0], ae1 = ae[1], b0 = battn[0];

    float s0a[8], s1a[8];
    unsigned long long mK[8];
    #pragma unroll
    for (int j = 0; j < 8; ++j) {
        s0a[j] = NEGSENT; s1a[j] = NEGSENT;
        unsigned long long m = mA[j] | mO[j];
        while (m) {
            int bit = __builtin_ctzll(m); m &= m - 1;
            int gs = base + (j << 6) + bit;
            f32x4 y = *(const f32x4*)(node + (size_t)gs * 256 + (lane << 2));
            float p = xt4.x * y.x + xt4.y * y.y + xt4.z * y.z + xt4.w * y.w;
            #pragma unroll
            for (int o = 32; o; o >>= 1) p += __shfl_xor(p, o);
            if (p > 0.f && lane == bit) {
                float bs = a_t + asr[gs] + b0;
                if ((mA[j] >> bit) & 1) s0a[j] = bs + ae0;
                if ((mO[j] >> bit) & 1) s1a[j] = bs + ae1;
            }
        }
        mK[j] = __ballot(s0a[j] > -1e29f || s1a[j] > -1e29f);
    }

    float mx = NEGSENT;
    #pragma unroll
    for (int j = 0; j < 8; ++j) mx = fmaxf(mx, fmaxf(s0a[j], s1a[j]));
    #pragma unroll
    for (int o = 32; o; o >>= 1) mx = fmaxf(mx, __shfl_xor(mx, o));
    bool has = mx > -1e29f;

    float se0 = 0.f, se1 = 0.f;
    #pragma unroll
    for (int j = 0; j < 8; ++j) {
        se0 += expf(s0a[j] - mx);
        se1 += expf(s1a[j] - mx);
    }
    #pragma unroll
    for (int o = 32; o; o >>= 1) { se0 += __shfl_xor(se0, o); se1 += __shfl_xor(se1, o); }
    float rden = 1.f / (se0 + se1);

    f32x4 res;
    if (has) {
        f32x4 agg4 = {0.f, 0.f, 0.f, 0.f};
        #pragma unroll
        for (int j = 0; j < 8; ++j) {
            unsigned long long m = mK[j];
            while (m) {
                int bit = __builtin_ctzll(m); m &= m - 1;
                int gs = base + (j << 6) + bit;
                float w0 = __shfl(s0a[j], bit);
                float w1 = __shfl(s1a[j], bit);
                float wt = (expf(w0 - mx) + expf(w1 - mx)) * rden;
                const f32x4 nw = *(const f32x4*)(nodeW + (size_t)gs * 256 + (lane << 2));
                agg4.x += wt * nw.x; agg4.y += wt * nw.y;
                agg4.z += wt * nw.z; agg4.w += wt * nw.w;
            }
        }
        f32x4 v1 = *(const f32x4*)(ve + (lane << 2));
        f32x4 v2 = *(const f32x4*)(ve + 256 + (lane << 2));
        f32x4 bg = *(const f32x4*)(bgat + (lane << 2));
        float c0 = se0 * rden, c1 = se1 * rden;
        res.x = fmaxf(agg4.x + c0 * v1.x + c1 * v2.x + bg.x, 0.f);
        res.y = fmaxf(agg4.y + c0 * v1.y + c1 * v2.y + bg.y, 0.f);
        res.z = fmaxf(agg4.z + c0 * v1.z + c1 * v2.z + bg.z, 0.f);
        res.w = fmaxf(agg4.w + c0 * v1.w + c1 * v2.w + bg.w, 0.f);
        if (lane == 0) bflag[b] = 1;
    } else {
        res = xt4;
    }
    *(f32x4*)(nadd + (size_t)tgt * 256 + (lane << 2)) = res;
}

// ---------------- out rows<128: emb + ballot-gathered scatter-add ----------------
__global__ __launch_bounds__(256) void k_scatter(const float* __restrict__ emb,
        const float* __restrict__ nadd,
        const int* __restrict__ ast, const int* __restrict__ ost,
        const int* __restrict__ bflag, float* __restrict__ out) {
    int b = blockIdx.x >> 7;
    int r = blockIdx.x & 127;
    int tid = threadIdx.x;

    __shared__ int cen[512];
    __shared__ unsigned long long s_mask[8];
    for (int n = tid; n < 512; n += 256)
        cen[n] = (ast[(b << 9) + n] + ost[(b << 9) + n]) >> 1;
    __syncthreads();
    #pragma unroll
    for (int p = 0; p < 2; ++p) {
        int n = tid + (p << 8);
        unsigned long long bal = __ballot(cen[n] == r);
        if ((tid & 63) == 0) s_mask[(p << 2) + (tid >> 6)] = bal;
    }
    __syncthreads();
    size_t o = ((size_t)b * Ln + r) * 256 + tid;
    float acc = emb[o];
    if (bflag[b]) {
        for (int w = 0; w < 8; ++w) {
            unsigned long long m = s_mask[w];
            while (m) {
                int n = (w << 6) + __builtin_ctzll(m); m &= m - 1;
                acc += nadd[((size_t)(b << 9) + n) * 256 + tid];
            }
        }
    }
    out[o] = acc;
}

extern "C" void kernel_launch(void* const* d_in, const int* in_sizes, int n_in,
                              void* d_out, int out_size, void* d_ws, size_t ws_size,
                              hipStream_t stream) {
    const float* emb   = (const float*)d_in[0];
    const float* Wtrip = (const float*)d_in[1];
    const float* btrip = (const float*)d_in[2];
    const float* Eemb  = (const float*)d_in[3];
    const float* Wattn = (const float*)d_in[4];
    const float* battn = (const float*)d_in[5];
    const float* Wgat  = (const float*)d_in[6];
    const float* bgat  = (const float*)d_in[7];
    const int* ast  = (const int*)d_in[8];
    const int* alen = (const int*)d_in[9];
    const int* ost  = (const int*)d_in[10];
    const int* olen = (const int*)d_in[11];
    const int* sid  = (const int*)d_in[12];
    float* out = (float*)d_out;

    float* ws    = (float*)d_ws;
    float* PQ    = ws;                                    // [4352*1024] 17.8 MB
    float* node  = PQ + (size_t)4352 * 1024;              // [ROWS*256]
    float* nodeW = node + (size_t)ROWS * 256;             // [ROWS*256]
    float* nadd  = nodeW + (size_t)ROWS * 256;            // [ROWS*256]
    float* WtG   = nadd + (size_t)ROWS * 256;             // [2*256*256]
    float* W3g   = WtG + 2 * 65536;                       // [3*256]
    float* btg   = W3g + 768;                             // [256]
    float* atg   = btg + 256;                             // [ROWS]
    float* asr   = atg + ROWS;                            // [ROWS]
    float* ae    = asr + ROWS;                            // [2]
    float* ve    = ae + 2;                                // [512]
    int* bflag   = (int*)(ve + 512);                      // [Bn]
    int* keys    = bflag + Bn;                            // [ROWS]

    k_pre<<<1024, 256, 0, stream>>>(Wtrip, btrip, Eemb, Wattn, Wgat,
                                    ast, alen, ost, olen, emb, out,
                                    WtG, W3g, btg, ae, ve, keys, bflag);
    k_pq<<<dim3(68, 16), 256, 0, stream>>>(emb, Wtrip, WtG, PQ, out);
    k_combine<<<ROWS / 4, 256, 0, stream>>>(PQ, Wtrip, btrip, sid,
                                            ast, alen, ost, olen,
                                            Wattn, W3g, btg, emb, out, node, nodeW,
                                            atg, asr);
    k_edges<<<ROWS / 4, 256, 0, stream>>>(node, nodeW, atg, asr, ae, battn, ve, bgat,
                                          keys, emb, out, nadd, bflag);
    k_scatter<<<Bn * 128, 256, 0, stream>>>(emb, nadd, ast, ost, bflag, out);
}

// Round 16
// 142.247 us; speedup vs baseline: 1.2584x; 1.0291x over previous
//
#include <hip/hip_runtime.h>
#include <math.h>

#define Bn 32
#define Ln 4096
#define ROWS 16384
#define LR 136
#define SLOPEC 0.2f
#define NEGSENT -1e30f
// Linear full-buffer copy: 8,388,608 f32x4 slots.
// k_pre [0, 2097152) | k_pq [2097152, 3211264) | k_combine [3211264, 6356992)
// k_edges [6356992, 8388608). Rows<128 overwritten by k_scatter.

typedef __attribute__((ext_vector_type(4))) float f32x4;
typedef __attribute__((ext_vector_type(4))) unsigned short u16x4;

__device__ __forceinline__ void copy_lin(const float* __restrict__ emb,
        float* __restrict__ out, long start, int count, int tid) {
    const f32x4* s4 = (const f32x4*)emb;
    f32x4* d4 = (f32x4*)out;
    for (int i = tid; i < count; i += 256)
        d4[start + i] = s4[start + i];
}

__device__ __forceinline__ f32x4 leaky4(f32x4 v) {
    f32x4 r;
    r.x = v.x >= 0.f ? v.x : SLOPEC * v.x;
    r.y = v.y >= 0.f ? v.y : SLOPEC * v.y;
    r.z = v.z >= 0.f ? v.z : SLOPEC * v.z;
    r.w = v.w >= 0.f ? v.w : SLOPEC * v.w;
    return r;
}

__device__ __forceinline__ f32x4 bf4_to_f32(u16x4 h) {
    union { unsigned int u; float f; } t;
    f32x4 r;
    t.u = (unsigned)h.x << 16; r.x = t.f;
    t.u = (unsigned)h.y << 16; r.y = t.f;
    t.u = (unsigned)h.z << 16; r.z = t.f;
    t.u = (unsigned)h.w << 16; r.w = t.f;
    return r;
}

__device__ __forceinline__ unsigned short f_to_bf16(float f) {
    union { float f; unsigned int u; } t;
    t.f = f;
    unsigned int u = t.u;
    u += 0x7FFFu + ((u >> 16) & 1u);   // round-to-nearest-even
    return (unsigned short)(u >> 16);
}

// ---------------- pre: WtG, W3g, btg, ae, ve, keys, bflag + copy share ----------------
__global__ __launch_bounds__(256) void k_pre(const float* __restrict__ Wtrip,
        const float* __restrict__ btrip, const float* __restrict__ Eemb,
        const float* __restrict__ Wattn, const float* __restrict__ Wgat,
        const int* __restrict__ ast, const int* __restrict__ alen,
        const int* __restrict__ ost, const int* __restrict__ olen,
        const float* __restrict__ emb, float* __restrict__ out,
        float* __restrict__ WtG, float* __restrict__ W3g, float* __restrict__ btg,
        float* __restrict__ ae, float* __restrict__ ve,
        int* __restrict__ keys, int* __restrict__ bflag) {
    int bid = blockIdx.x, tid = threadIdx.x;
    copy_lin(emb, out, (long)bid * 2048, 2048, tid);
    __shared__ float Als[32][68];
    __shared__ float Bls[32][64];
    __shared__ float red[4];
    __shared__ float vr0[8][32], vr1[8][32];
    if (bid < 32) {
        int mat = bid >> 4, t = bid & 15;
        int m0 = (t >> 2) << 6, n0 = (t & 3) << 6;
        const float* A = Wtrip + mat * 65536;
        int r0 = (tid & 15) << 2, c0 = (tid >> 4) << 2;
        float acc[4][4] = {};
        for (int kk = 0; kk < 256; kk += 32) {
            __syncthreads();
            #pragma unroll
            for (int p = 0; p < 2; ++p) {
                int idx = tid + (p << 8);
                int row = idx >> 3, kq = (idx & 7) << 2;
                const float4 v = *(const float4*)(A + (size_t)(m0 + row) * 256 + kk + kq);
                Als[kq + 0][row] = v.x; Als[kq + 1][row] = v.y;
                Als[kq + 2][row] = v.z; Als[kq + 3][row] = v.w;
            }
            #pragma unroll
            for (int p = 0; p < 2; ++p) {
                int idx = tid + (p << 8);
                int k = idx >> 4, hq = (idx & 15) << 2;
                *(float4*)(&Bls[k][hq]) = *(const float4*)(Wgat + (size_t)(kk + k) * 256 + n0 + hq);
            }
            __syncthreads();
            #pragma unroll
            for (int k = 0; k < 32; ++k) {
                float4 a  = *(const float4*)(&Als[k][r0]);
                float4 bv = *(const float4*)(&Bls[k][c0]);
                acc[0][0] += a.x*bv.x; acc[0][1] += a.x*bv.y; acc[0][2] += a.x*bv.z; acc[0][3] += a.x*bv.w;
                acc[1][0] += a.y*bv.x; acc[1][1] += a.y*bv.y; acc[1][2] += a.y*bv.z; acc[1][3] += a.y*bv.w;
                acc[2][0] += a.z*bv.x; acc[2][1] += a.z*bv.y; acc[2][2] += a.z*bv.z; acc[2][3] += a.z*bv.w;
                acc[3][0] += a.w*bv.x; acc[3][1] += a.w*bv.y; acc[3][2] += a.w*bv.z; acc[3][3] += a.w*bv.w;
            }
        }
        #pragma unroll
        for (int i = 0; i < 4; ++i)
            #pragma unroll
            for (int j = 0; j < 4; ++j)
                WtG[mat * 65536 + (size_t)(m0 + r0 + i) * 256 + n0 + c0 + j] = acc[i][j];
    } else if (bid == 32) {
        float s = 0.f;
        for (int k = 0; k < 256; ++k) s += btrip[k] * Wgat[(size_t)k * 256 + tid];
        btg[tid] = s;
    } else if (bid == 33) {
        if (tid < Bn) bflag[tid] = 0;
        #pragma unroll
        for (int e = 0; e < 2; ++e) {
            float x = Eemb[e * 256 + tid];
            float lx = x >= 0.f ? x : SLOPEC * x;
            float s = lx * Wattn[512 + tid];
            #pragma unroll
            for (int o = 32; o; o >>= 1) s += __shfl_down(s, o);
            if ((tid & 63) == 0) red[tid >> 6] = s;
            __syncthreads();
            if (tid == 0) ae[e] = red[0] + red[1] + red[2] + red[3];
            __syncthreads();
        }
    } else if (bid < 37) {
        int s = bid - 34;
        float acc = 0.f;
        for (int k = 0; k < 256; ++k)
            acc += Wtrip[(size_t)(512 + s) * 256 + k] * Wgat[(size_t)k * 256 + tid];
        W3g[s * 256 + tid] = acc;
    } else if (bid < 45) {
        int j = bid - 37;
        int n0 = j << 5;
        int nl = tid & 31, kg = tid >> 5;
        float p0 = 0.f, p1 = 0.f;
        for (int kk = 0; kk < 32; ++kk) {
            int k = (kg << 5) + kk;
            float w = Wgat[(size_t)(256 + k) * 256 + n0 + nl];
            p0 += Eemb[k] * w;
            p1 += Eemb[256 + k] * w;
        }
        vr0[kg][nl] = p0; vr1[kg][nl] = p1;
        __syncthreads();
        if (tid < 32) {
            float s0 = 0.f, s1 = 0.f;
            #pragma unroll
            for (int g = 0; g < 8; ++g) { s0 += vr0[g][tid]; s1 += vr1[g][tid]; }
            ve[n0 + tid] = s0;
            ve[256 + n0 + tid] = s1;
        }
    } else if (bid < 109) {
        int row = (bid - 45) * 256 + tid;
        keys[row] = (((ast[row] << 3) | alen[row]) << 10) | ((ost[row] << 3) | olen[row]);
    }
}

// ---------------- PQf = emb135 @ [Wtop|Wbot] (fp32, sign path, j<8)
//                  PQh = emb135 @ [WtopG|WbotG] (bf16 store, agg path, j>=8)
//                  + copy share ----------------
__global__ __launch_bounds__(256) void k_pq(const float* __restrict__ emb,
        const float* __restrict__ Wtrip, const float* __restrict__ WtG,
        float* __restrict__ PQf, unsigned short* __restrict__ PQh,
        float* __restrict__ out) {
    __shared__ float Als[32][68];
    __shared__ float Bls[32][64];
    int tid = threadIdx.x;
    {
        int bid = blockIdx.y * 68 + blockIdx.x;   // 1088 blocks x 1024 slots
        copy_lin(emb, out, 2097152L + (long)bid * 1024, 1024, tid);
    }
    int m0 = blockIdx.x << 6;
    int j = blockIdx.y;   // n-tile 0..15
    const float* Bp;
    if (j < 4)       Bp = Wtrip + (j << 6);
    else if (j < 8)  Bp = Wtrip + 65536 + ((j - 4) << 6);
    else if (j < 12) Bp = WtG + ((j - 8) << 6);
    else             Bp = WtG + 65536 + ((j - 12) << 6);
    int r0 = (tid & 15) << 2;
    int c0 = (tid >> 4) << 2;
    float acc[4][4] = {};
    for (int kk = 0; kk < 256; kk += 32) {
        __syncthreads();
        #pragma unroll
        for (int p = 0; p < 2; ++p) {   // A: 64 rows x 32 k (k-major LDS)
            int idx = tid + (p << 8);
            int row = idx >> 3;
            int kq = (idx & 7) << 2;
            int m = m0 + row;
            int b = m / LR;
            int l = m - b * LR;
            const float4 v = *(const float4*)(emb + (size_t)(b * Ln + l) * 256 + kk + kq);
            Als[kq + 0][row] = v.x; Als[kq + 1][row] = v.y;
            Als[kq + 2][row] = v.z; Als[kq + 3][row] = v.w;
        }
        #pragma unroll
        for (int p = 0; p < 2; ++p) {   // B: 32 k x 64 cols
            int idx = tid + (p << 8);
            int k = idx >> 4;
            int hq = (idx & 15) << 2;
            *(float4*)(&Bls[k][hq]) = *(const float4*)(Bp + (size_t)(kk + k) * 256 + hq);
        }
        __syncthreads();
        #pragma unroll
        for (int k = 0; k < 32; ++k) {
            float4 a  = *(const float4*)(&Als[k][r0]);
            float4 bv = *(const float4*)(&Bls[k][c0]);
            acc[0][0] += a.x*bv.x; acc[0][1] += a.x*bv.y; acc[0][2] += a.x*bv.z; acc[0][3] += a.x*bv.w;
            acc[1][0] += a.y*bv.x; acc[1][1] += a.y*bv.y; acc[1][2] += a.y*bv.z; acc[1][3] += a.y*bv.w;
            acc[2][0] += a.z*bv.x; acc[2][1] += a.z*bv.y; acc[2][2] += a.z*bv.z; acc[2][3] += a.z*bv.w;
            acc[3][0] += a.w*bv.x; acc[3][1] += a.w*bv.y; acc[3][2] += a.w*bv.z; acc[3][3] += a.w*bv.w;
        }
    }
    if (j < 8) {
        #pragma unroll
        for (int i = 0; i < 4; ++i)
            #pragma unroll
            for (int jj = 0; jj < 4; ++jj)
                PQf[(size_t)(m0 + r0 + i) * 512 + (j << 6) + c0 + jj] = acc[i][jj];
    } else {
        #pragma unroll
        for (int i = 0; i < 4; ++i)
            #pragma unroll
            for (int jj = 0; jj < 4; ++jj)
                PQh[(size_t)(m0 + r0 + i) * 512 + ((j - 8) << 6) + c0 + jj] =
                    f_to_bf16(acc[i][jj]);
    }
}

// ---------------- combine: wave-per-row, XCD-swizzled, no barriers
//                  -> node (fp32), nodeWh (bf16), atg, asr + copy share ----------------
__global__ __launch_bounds__(256) void k_combine(const float* __restrict__ PQf,
        const unsigned short* __restrict__ PQh,
        const float* __restrict__ Wtrip, const float* __restrict__ btrip,
        const int* __restrict__ sid,
        const int* __restrict__ ast, const int* __restrict__ alen,
        const int* __restrict__ ost, const int* __restrict__ olen,
        const float* __restrict__ Wattn, const float* __restrict__ W3g,
        const float* __restrict__ btg, const float* __restrict__ emb,
        float* __restrict__ out, float* __restrict__ node,
        unsigned short* __restrict__ nodeWh,
        float* __restrict__ atg, float* __restrict__ asr) {
    int bid = blockIdx.x, tid = threadIdx.x;
    int wv = tid >> 6, lane = tid & 63;
    copy_lin(emb, out, 3211264L + (long)bid * 768, 768, tid);

    int s = ((bid & 7) << 9) | (bid >> 3);   // XCD swizzle: 4 whole batches per XCD
    int row = (s << 2) + wv;
    int b = row >> 9;
    int as_ = ast[row], al = alen[row];
    int os_ = ost[row], ol = olen[row];
    int c = lane << 2;
    const float* Pb = PQf + (size_t)b * LR * 512 + c;
    const unsigned short* Ph = PQh + (size_t)b * LR * 512 + c;

    f32x4 asum = {0.f,0.f,0.f,0.f}, osum = asum, p2 = asum, q2 = asum;
    for (int i = 0; i <= al; ++i) {
        size_t off = (size_t)(as_ + i) * 512;
        asum += *(const f32x4*)(Pb + off);
        p2   += bf4_to_f32(*(const u16x4*)(Ph + off));
    }
    for (int i = 0; i <= ol; ++i) {
        size_t off = (size_t)(os_ + i) * 512 + 256;
        osum += *(const f32x4*)(Pb + off);
        q2   += bf4_to_f32(*(const u16x4*)(Ph + off));
    }
    float ra = 1.f / (float)(al + 1), ro = 1.f / (float)(ol + 1);
    int sd = sid[row];

    f32x4 x = asum * ra + osum * ro
            + *(const f32x4*)(Wtrip + (size_t)(512 + sd) * 256 + c)
            + *(const f32x4*)(btrip + c);
    *(f32x4*)(node + (size_t)row * 256 + c) = x;

    f32x4 nw = p2 * ra + q2 * ro
             + *(const f32x4*)(W3g + sd * 256 + c)
             + *(const f32x4*)(btg + c);
    u16x4 nwh;
    nwh.x = f_to_bf16(nw.x); nwh.y = f_to_bf16(nw.y);
    nwh.z = f_to_bf16(nw.z); nwh.w = f_to_bf16(nw.w);
    *(u16x4*)(nodeWh + (size_t)row * 256 + c) = nwh;

    f32x4 lx = leaky4(x);
    f32x4 w1 = *(const f32x4*)(Wattn + c);
    f32x4 w2 = *(const f32x4*)(Wattn + 256 + c);
    float s1 = lx.x*w1.x + lx.y*w1.y + lx.z*w1.z + lx.w*w1.w;
    float s2 = lx.x*w2.x + lx.y*w2.y + lx.z*w2.z + lx.w*w2.w;
    #pragma unroll
    for (int o = 32; o; o >>= 1) {
        s1 += __shfl_xor(s1, o);
        s2 += __shfl_xor(s2, o);
    }
    if (lane == 0) { atg[row] = s1; asr[row] = s2; }
}

// ---------------- sparse edges: wave-per-target, XCD-swizzled, zero barriers
//                  bf16 nodeW gather + copy share ----------------
__global__ __launch_bounds__(256) void k_edges(
        const float* __restrict__ node, const unsigned short* __restrict__ nodeWh,
        const float* __restrict__ atg, const float* __restrict__ asr,
        const float* __restrict__ ae, const float* __restrict__ battn,
        const float* __restrict__ ve, const float* __restrict__ bgat,
        const int* __restrict__ keys,
        const float* __restrict__ emb, float* __restrict__ out,
        float* __restrict__ nadd, int* __restrict__ bflag) {
    int bid = blockIdx.x;
    int tid = threadIdx.x;
    int wv = tid >> 6, lane = tid & 63;

    copy_lin(emb, out, 6356992L + (long)bid * 496, 496, tid);

    int s = ((bid & 7) << 9) | (bid >> 3);   // XCD swizzle: 4 whole batches per XCD
    int tgt = (s << 2) + wv;
    int b = tgt >> 9, base = b << 9, lt = tgt & 511;

    int mykey = keys[tgt];
    int ka = mykey >> 10, ko = mykey & 1023;

    unsigned long long mA[8], mO[8];
    #pragma unroll
    for (int j = 0; j < 8; ++j) {
        int ls = (j << 6) + lane;
        int k2 = keys[base + ls];
        bool self = (ls == lt);
        mA[j] = __ballot(((k2 >> 10) == ka) && !self);
        mO[j] = __ballot(((k2 & 1023) == ko) && !self);
    }

    f32x4 xt4 = *(const f32x4*)(node + (size_t)tgt * 256 + (lane << 2));
    float a_t = atg[tgt];
    float ae0 = ae[0], ae1 = ae[1], b0 = battn[0];

    float s0a[8], s1a[8];
    unsigned long long mK[8];
    #pragma unroll
    for (int j = 0; j < 8; ++j) {
        s0a[j] = NEGSENT; s1a[j] = NEGSENT;
        unsigned long long m = mA[j] | mO[j];
        while (m) {
            int bit = __builtin_ctzll(m); m &= m - 1;
            int gs = base + (j << 6) + bit;
            f32x4 y = *(const f32x4*)(node + (size_t)gs * 256 + (lane << 2));
            float p = xt4.x * y.x + xt4.y * y.y + xt4.z * y.z + xt4.w * y.w;
            #pragma unroll
            for (int o = 32; o; o >>= 1) p += __shfl_xor(p, o);
            if (p > 0.f && lane == bit) {
                float bs = a_t + asr[gs] + b0;
                if ((mA[j] >> bit) & 1) s0a[j] = bs + ae0;
                if ((mO[j] >> bit) & 1) s1a[j] = bs + ae1;
            }
        }
        mK[j] = __ballot(s0a[j] > -1e29f || s1a[j] > -1e29f);
    }

    float mx = NEGSENT;
    #pragma unroll
    for (int j = 0; j < 8; ++j) mx = fmaxf(mx, fmaxf(s0a[j], s1a[j]));
    #pragma unroll
    for (int o = 32; o; o >>= 1) mx = fmaxf(mx, __shfl_xor(mx, o));
    bool has = mx > -1e29f;

    float se0 = 0.f, se1 = 0.f;
    #pragma unroll
    for (int j = 0; j < 8; ++j) {
        se0 += expf(s0a[j] - mx);
        se1 += expf(s1a[j] - mx);
    }
    #pragma unroll
    for (int o = 32; o; o >>= 1) { se0 += __shfl_xor(se0, o); se1 += __shfl_xor(se1, o); }
    float rden = 1.f / (se0 + se1);

    f32x4 res;
    if (has) {
        f32x4 agg4 = {0.f, 0.f, 0.f, 0.f};
        #pragma unroll
        for (int j = 0; j < 8; ++j) {
            unsigned long long m = mK[j];
            while (m) {
                int bit = __builtin_ctzll(m); m &= m - 1;
                int gs = base + (j << 6) + bit;
                float w0 = __shfl(s0a[j], bit);
                float w1 = __shfl(s1a[j], bit);
                float wt = (expf(w0 - mx) + expf(w1 - mx)) * rden;
                f32x4 nw = bf4_to_f32(*(const u16x4*)(nodeWh + (size_t)gs * 256 + (lane << 2)));
                agg4.x += wt * nw.x; agg4.y += wt * nw.y;
                agg4.z += wt * nw.z; agg4.w += wt * nw.w;
            }
        }
        f32x4 v1 = *(const f32x4*)(ve + (lane << 2));
        f32x4 v2 = *(const f32x4*)(ve + 256 + (lane << 2));
        f32x4 bg = *(const f32x4*)(bgat + (lane << 2));
        float c0 = se0 * rden, c1 = se1 * rden;
        res.x = fmaxf(agg4.x + c0 * v1.x + c1 * v2.x + bg.x, 0.f);
        res.y = fmaxf(agg4.y + c0 * v1.y + c1 * v2.y + bg.y, 0.f);
        res.z = fmaxf(agg4.z + c0 * v1.z + c1 * v2.z + bg.z, 0.f);
        res.w = fmaxf(agg4.w + c0 * v1.w + c1 * v2.w + bg.w, 0.f);
        if (lane == 0) bflag[b] = 1;
    } else {
        res = xt4;
    }
    *(f32x4*)(nadd + (size_t)tgt * 256 + (lane << 2)) = res;
}

// ---------------- out rows<128: emb + ballot-gathered scatter-add ----------------
__global__ __launch_bounds__(256) void k_scatter(const float* __restrict__ emb,
        const float* __restrict__ nadd,
        const int* __restrict__ ast, const int* __restrict__ ost,
        const int* __restrict__ bflag, float* __restrict__ out) {
    int b = blockIdx.x >> 7;
    int r = blockIdx.x & 127;
    int tid = threadIdx.x;

    __shared__ int cen[512];
    __shared__ unsigned long long s_mask[8];
    for (int n = tid; n < 512; n += 256)
        cen[n] = (ast[(b << 9) + n] + ost[(b << 9) + n]) >> 1;
    __syncthreads();
    #pragma unroll
    for (int p = 0; p < 2; ++p) {
        int n = tid + (p << 8);
        unsigned long long bal = __ballot(cen[n] == r);
        if ((tid & 63) == 0) s_mask[(p << 2) + (tid >> 6)] = bal;
    }
    __syncthreads();
    size_t o = ((size_t)b * Ln + r) * 256 + tid;
    float acc = emb[o];
    if (bflag[b]) {
        for (int w = 0; w < 8; ++w) {
            unsigned long long m = s_mask[w];
            while (m) {
                int n = (w << 6) + __builtin_ctzll(m); m &= m - 1;
                acc += nadd[((size_t)(b << 9) + n) * 256 + tid];
            }
        }
    }
    out[o] = acc;
}

extern "C" void kernel_launch(void* const* d_in, const int* in_sizes, int n_in,
                              void* d_out, int out_size, void* d_ws, size_t ws_size,
                              hipStream_t stream) {
    const float* emb   = (const float*)d_in[0];
    const float* Wtrip = (const float*)d_in[1];
    const float* btrip = (const float*)d_in[2];
    const float* Eemb  = (const float*)d_in[3];
    const float* Wattn = (const float*)d_in[4];
    const float* battn = (const float*)d_in[5];
    const float* Wgat  = (const float*)d_in[6];
    const float* bgat  = (const float*)d_in[7];
    const int* ast  = (const int*)d_in[8];
    const int* alen = (const int*)d_in[9];
    const int* ost  = (const int*)d_in[10];
    const int* olen = (const int*)d_in[11];
    const int* sid  = (const int*)d_in[12];
    float* out = (float*)d_out;

    float* ws    = (float*)d_ws;
    float* PQf   = ws;                                    // [4352*512] fp32
    float* node  = PQf + (size_t)4352 * 512;              // [ROWS*256] fp32
    float* nadd  = node + (size_t)ROWS * 256;             // [ROWS*256] fp32
    float* WtG   = nadd + (size_t)ROWS * 256;             // [2*256*256] fp32
    float* W3g   = WtG + 2 * 65536;                       // [3*256]
    float* btg   = W3g + 768;                             // [256]
    float* atg   = btg + 256;                             // [ROWS]
    float* asr   = atg + ROWS;                            // [ROWS]
    float* ae    = asr + ROWS;                            // [2]
    float* ve    = ae + 2;                                // [512]
    int* bflag   = (int*)(ve + 512);                      // [Bn]
    int* keys    = bflag + Bn;                            // [ROWS]
    unsigned short* PQh    = (unsigned short*)(keys + ROWS + 32);   // [4352*512] bf16
    unsigned short* nodeWh = PQh + (size_t)4352 * 512;              // [ROWS*256] bf16

    k_pre<<<1024, 256, 0, stream>>>(Wtrip, btrip, Eemb, Wattn, Wgat,
                                    ast, alen, ost, olen, emb, out,
                                    WtG, W3g, btg, ae, ve, keys, bflag);
    k_pq<<<dim3(68, 16), 256, 0, stream>>>(emb, Wtrip, WtG, PQf, PQh, out);
    k_combine<<<ROWS / 4, 256, 0, stream>>>(PQf, PQh, Wtrip, btrip, sid,
                                            ast, alen, ost, olen,
                                            Wattn, W3g, btg, emb, out, node, nodeWh,
                                            atg, asr);
    k_edges<<<ROWS / 4, 256, 0, stream>>>(node, nodeWh, atg, asr, ae, battn, ve, bgat,
                                          keys, emb, out, nadd, bflag);
    k_scatter<<<Bn * 128, 256, 0, stream>>>(emb, nadd, ast, ost, bflag, out);
}

// Round 17
// 131.425 us; speedup vs baseline: 1.3620x; 1.0823x over previous
//
#include <hip/hip_runtime.h>
#include <math.h>

#define Bn 32
#define Ln 4096
#define ROWS 16384
#define LR 136
#define SLOPEC 0.2f
#define NEGSENT -1e30f
// Linear full-buffer copy: 8,388,608 f32x4 slots.
// k_pre [0, 2097152) | k_pq [2097152, 3211264) | k_combine [3211264, 6356992)
// k_edges [6356992, 8388608). Rows<128 overwritten by k_scatter.

typedef __attribute__((ext_vector_type(4))) float f32x4;
typedef __attribute__((ext_vector_type(4))) unsigned short u16x4;
typedef __attribute__((ext_vector_type(8))) short bf16x8;

__device__ __forceinline__ void copy_lin(const float* __restrict__ emb,
        float* __restrict__ out, long start, int count, int tid) {
    const f32x4* s4 = (const f32x4*)emb;
    f32x4* d4 = (f32x4*)out;
    for (int i = tid; i < count; i += 256)
        d4[start + i] = s4[start + i];
}

__device__ __forceinline__ f32x4 leaky4(f32x4 v) {
    f32x4 r;
    r.x = v.x >= 0.f ? v.x : SLOPEC * v.x;
    r.y = v.y >= 0.f ? v.y : SLOPEC * v.y;
    r.z = v.z >= 0.f ? v.z : SLOPEC * v.z;
    r.w = v.w >= 0.f ? v.w : SLOPEC * v.w;
    return r;
}

__device__ __forceinline__ f32x4 bf4_to_f32(u16x4 h) {
    union { unsigned int u; float f; } t;
    f32x4 r;
    t.u = (unsigned)h.x << 16; r.x = t.f;
    t.u = (unsigned)h.y << 16; r.y = t.f;
    t.u = (unsigned)h.z << 16; r.z = t.f;
    t.u = (unsigned)h.w << 16; r.w = t.f;
    return r;
}

__device__ __forceinline__ unsigned short f_to_bf16(float f) {
    union { float f; unsigned int u; } t;
    t.f = f;
    unsigned int u = t.u;
    u += 0x7FFFu + ((u >> 16) & 1u);   // round-to-nearest-even
    return (unsigned short)(u >> 16);
}

// ---------------- pre: WtGT(bf16,T), embh(bf16), W3g, btg, ae, ve, keys, bflag
//                  + copy share ----------------
__global__ __launch_bounds__(256) void k_pre(const float* __restrict__ Wtrip,
        const float* __restrict__ btrip, const float* __restrict__ Eemb,
        const float* __restrict__ Wattn, const float* __restrict__ Wgat,
        const int* __restrict__ ast, const int* __restrict__ alen,
        const int* __restrict__ ost, const int* __restrict__ olen,
        const float* __restrict__ emb, float* __restrict__ out,
        unsigned short* __restrict__ WtGT, unsigned short* __restrict__ embh,
        float* __restrict__ W3g, float* __restrict__ btg,
        float* __restrict__ ae, float* __restrict__ ve,
        int* __restrict__ keys, int* __restrict__ bflag) {
    int bid = blockIdx.x, tid = threadIdx.x;
    copy_lin(emb, out, (long)bid * 2048, 2048, tid);
    __shared__ float Als[32][68];
    __shared__ float Bls[32][64];
    __shared__ float red[4];
    __shared__ float vr0[8][32], vr1[8][32];
    if (bid < 32) {
        // WtG[mat][h][c] = sum_n Wtrip[mat*256+h][n]*Wgat[n][c]; store bf16 TRANSPOSED:
        // WtGT[(mat*256 + c)*256 + h]
        int mat = bid >> 4, t = bid & 15;
        int m0 = (t >> 2) << 6, n0 = (t & 3) << 6;
        const float* A = Wtrip + mat * 65536;
        int r0 = (tid & 15) << 2, c0 = (tid >> 4) << 2;
        float acc[4][4] = {};
        for (int kk = 0; kk < 256; kk += 32) {
            __syncthreads();
            #pragma unroll
            for (int p = 0; p < 2; ++p) {
                int idx = tid + (p << 8);
                int row = idx >> 3, kq = (idx & 7) << 2;
                const float4 v = *(const float4*)(A + (size_t)(m0 + row) * 256 + kk + kq);
                Als[kq + 0][row] = v.x; Als[kq + 1][row] = v.y;
                Als[kq + 2][row] = v.z; Als[kq + 3][row] = v.w;
            }
            #pragma unroll
            for (int p = 0; p < 2; ++p) {
                int idx = tid + (p << 8);
                int k = idx >> 4, hq = (idx & 15) << 2;
                *(float4*)(&Bls[k][hq]) = *(const float4*)(Wgat + (size_t)(kk + k) * 256 + n0 + hq);
            }
            __syncthreads();
            #pragma unroll
            for (int k = 0; k < 32; ++k) {
                float4 a  = *(const float4*)(&Als[k][r0]);
                float4 bv = *(const float4*)(&Bls[k][c0]);
                acc[0][0] += a.x*bv.x; acc[0][1] += a.x*bv.y; acc[0][2] += a.x*bv.z; acc[0][3] += a.x*bv.w;
                acc[1][0] += a.y*bv.x; acc[1][1] += a.y*bv.y; acc[1][2] += a.y*bv.z; acc[1][3] += a.y*bv.w;
                acc[2][0] += a.z*bv.x; acc[2][1] += a.z*bv.y; acc[2][2] += a.z*bv.z; acc[2][3] += a.z*bv.w;
                acc[3][0] += a.w*bv.x; acc[3][1] += a.w*bv.y; acc[3][2] += a.w*bv.z; acc[3][3] += a.w*bv.w;
            }
        }
        #pragma unroll
        for (int i = 0; i < 4; ++i)
            #pragma unroll
            for (int j = 0; j < 4; ++j)
                WtGT[(size_t)(mat * 256 + n0 + c0 + j) * 256 + m0 + r0 + i] =
                    f_to_bf16(acc[i][j]);
    } else if (bid == 32) {
        float s = 0.f;
        for (int k = 0; k < 256; ++k) s += btrip[k] * Wgat[(size_t)k * 256 + tid];
        btg[tid] = s;
    } else if (bid == 33) {
        if (tid < Bn) bflag[tid] = 0;
        #pragma unroll
        for (int e = 0; e < 2; ++e) {
            float x = Eemb[e * 256 + tid];
            float lx = x >= 0.f ? x : SLOPEC * x;
            float s = lx * Wattn[512 + tid];
            #pragma unroll
            for (int o = 32; o; o >>= 1) s += __shfl_down(s, o);
            if ((tid & 63) == 0) red[tid >> 6] = s;
            __syncthreads();
            if (tid == 0) ae[e] = red[0] + red[1] + red[2] + red[3];
            __syncthreads();
        }
    } else if (bid < 37) {
        int s = bid - 34;
        float acc = 0.f;
        for (int k = 0; k < 256; ++k)
            acc += Wtrip[(size_t)(512 + s) * 256 + k] * Wgat[(size_t)k * 256 + tid];
        W3g[s * 256 + tid] = acc;
    } else if (bid < 45) {
        int j = bid - 37;
        int n0 = j << 5;
        int nl = tid & 31, kg = tid >> 5;
        float p0 = 0.f, p1 = 0.f;
        for (int kk = 0; kk < 32; ++kk) {
            int k = (kg << 5) + kk;
            float w = Wgat[(size_t)(256 + k) * 256 + n0 + nl];
            p0 += Eemb[k] * w;
            p1 += Eemb[256 + k] * w;
        }
        vr0[kg][nl] = p0; vr1[kg][nl] = p1;
        __syncthreads();
        if (tid < 32) {
            float s0 = 0.f, s1 = 0.f;
            #pragma unroll
            for (int g = 0; g < 8; ++g) { s0 += vr0[g][tid]; s1 += vr1[g][tid]; }
            ve[n0 + tid] = s0;
            ve[256 + n0 + tid] = s1;
        }
    } else if (bid < 109) {
        int row = (bid - 45) * 256 + tid;
        keys[row] = (((ast[row] << 3) | alen[row]) << 10) | ((ost[row] << 3) | olen[row]);
    } else if (bid < 381) {
        // embh: bf16 of emb135 [4352][256]; 272 blocks x 16 rows, coalesced
        int rbase = (bid - 109) << 4;
        #pragma unroll
        for (int i = 0; i < 16; ++i) {
            int row = rbase + i;
            int b2 = row / LR, l2 = row - b2 * LR;
            embh[(size_t)row * 256 + tid] =
                f_to_bf16(emb[((size_t)b2 * Ln + l2) * 256 + tid]);
        }
    }
}

// ---------------- k_pq: j<8 fp32 tile GEMM -> PQf (sign path)
//                  j>=8 bf16 MFMA (embh @ WtGT^T) -> PQh (agg path)
//                  + copy share ----------------
__global__ __launch_bounds__(256) void k_pq(const float* __restrict__ emb,
        const float* __restrict__ Wtrip,
        const unsigned short* __restrict__ embh, const unsigned short* __restrict__ WtGT,
        float* __restrict__ PQf, unsigned short* __restrict__ PQh,
        float* __restrict__ out) {
    __shared__ float Als[32][68];
    __shared__ float Bls[32][64];
    int tid = threadIdx.x;
    {
        int bid = blockIdx.y * 68 + blockIdx.x;   // 1088 blocks x 1024 slots
        copy_lin(emb, out, 2097152L + (long)bid * 1024, 1024, tid);
    }
    int m0 = blockIdx.x << 6;
    int j = blockIdx.y;   // n-tile 0..15

    if (j < 8) {
        const float* Bp = Wtrip + ((j < 4) ? (j << 6) : (65536 + ((j - 4) << 6)));
        int r0 = (tid & 15) << 2;
        int c0 = (tid >> 4) << 2;
        float acc[4][4] = {};
        for (int kk = 0; kk < 256; kk += 32) {
            __syncthreads();
            #pragma unroll
            for (int p = 0; p < 2; ++p) {   // A: 64 rows x 32 k (k-major LDS)
                int idx = tid + (p << 8);
                int row = idx >> 3;
                int kq = (idx & 7) << 2;
                int m = m0 + row;
                int b = m / LR;
                int l = m - b * LR;
                const float4 v = *(const float4*)(emb + (size_t)(b * Ln + l) * 256 + kk + kq);
                Als[kq + 0][row] = v.x; Als[kq + 1][row] = v.y;
                Als[kq + 2][row] = v.z; Als[kq + 3][row] = v.w;
            }
            #pragma unroll
            for (int p = 0; p < 2; ++p) {   // B: 32 k x 64 cols
                int idx = tid + (p << 8);
                int k = idx >> 4;
                int hq = (idx & 15) << 2;
                *(float4*)(&Bls[k][hq]) = *(const float4*)(Bp + (size_t)(kk + k) * 256 + hq);
            }
            __syncthreads();
            #pragma unroll
            for (int k = 0; k < 32; ++k) {
                float4 a  = *(const float4*)(&Als[k][r0]);
                float4 bv = *(const float4*)(&Bls[k][c0]);
                acc[0][0] += a.x*bv.x; acc[0][1] += a.x*bv.y; acc[0][2] += a.x*bv.z; acc[0][3] += a.x*bv.w;
                acc[1][0] += a.y*bv.x; acc[1][1] += a.y*bv.y; acc[1][2] += a.y*bv.z; acc[1][3] += a.y*bv.w;
                acc[2][0] += a.z*bv.x; acc[2][1] += a.z*bv.y; acc[2][2] += a.z*bv.z; acc[2][3] += a.z*bv.w;
                acc[3][0] += a.w*bv.x; acc[3][1] += a.w*bv.y; acc[3][2] += a.w*bv.z; acc[3][3] += a.w*bv.w;
            }
        }
        #pragma unroll
        for (int i = 0; i < 4; ++i)
            #pragma unroll
            for (int jj = 0; jj < 4; ++jj)
                PQf[(size_t)(m0 + r0 + i) * 512 + (j << 6) + c0 + jj] = acc[i][jj];
    } else {
        // bf16 MFMA: PQh[m][n] = sum_k embh[m][k] * WtG[k][n], WtGT[n][k] layout
        int jn = j - 8;
        int wv = tid >> 6, lane = tid & 63;
        int m0w = m0 + (wv << 4);
        int n0 = jn << 6;
        int fr = lane & 15;
        int kq = (lane >> 4) << 3;
        f32x4 acc2[4] = {};
        for (int k0 = 0; k0 < 256; k0 += 32) {
            bf16x8 a = *(const bf16x8*)(embh + (size_t)(m0w + fr) * 256 + k0 + kq);
            #pragma unroll
            for (int nf = 0; nf < 4; ++nf) {
                bf16x8 bfr = *(const bf16x8*)(WtGT + (size_t)(n0 + (nf << 4) + fr) * 256 + k0 + kq);
                acc2[nf] = __builtin_amdgcn_mfma_f32_16x16x32_bf16(a, bfr, acc2[nf], 0, 0, 0);
            }
        }
        int r0w = (lane >> 4) << 2;
        #pragma unroll
        for (int nf = 0; nf < 4; ++nf)
            #pragma unroll
            for (int r = 0; r < 4; ++r)
                PQh[(size_t)(m0w + r0w + r) * 512 + n0 + (nf << 4) + fr] =
                    f_to_bf16(acc2[nf][r]);
    }
}

// ---------------- combine: wave-per-row, XCD-swizzled, no barriers
//                  -> node (fp32), nodeWh (bf16), atg, asr + copy share ----------------
__global__ __launch_bounds__(256) void k_combine(const float* __restrict__ PQf,
        const unsigned short* __restrict__ PQh,
        const float* __restrict__ Wtrip, const float* __restrict__ btrip,
        const int* __restrict__ sid,
        const int* __restrict__ ast, const int* __restrict__ alen,
        const int* __restrict__ ost, const int* __restrict__ olen,
        const float* __restrict__ Wattn, const float* __restrict__ W3g,
        const float* __restrict__ btg, const float* __restrict__ emb,
        float* __restrict__ out, float* __restrict__ node,
        unsigned short* __restrict__ nodeWh,
        float* __restrict__ atg, float* __restrict__ asr) {
    int bid = blockIdx.x, tid = threadIdx.x;
    int wv = tid >> 6, lane = tid & 63;
    copy_lin(emb, out, 3211264L + (long)bid * 768, 768, tid);

    int s = ((bid & 7) << 9) | (bid >> 3);   // XCD swizzle: 4 whole batches per XCD
    int row = (s << 2) + wv;
    int b = row >> 9;
    int as_ = ast[row], al = alen[row];
    int os_ = ost[row], ol = olen[row];
    int c = lane << 2;
    const float* Pb = PQf + (size_t)b * LR * 512 + c;
    const unsigned short* Ph = PQh + (size_t)b * LR * 512 + c;

    f32x4 asum = {0.f,0.f,0.f,0.f}, osum = asum, p2 = asum, q2 = asum;
    for (int i = 0; i <= al; ++i) {
        size_t off = (size_t)(as_ + i) * 512;
        asum += *(const f32x4*)(Pb + off);
        p2   += bf4_to_f32(*(const u16x4*)(Ph + off));
    }
    for (int i = 0; i <= ol; ++i) {
        size_t off = (size_t)(os_ + i) * 512 + 256;
        osum += *(const f32x4*)(Pb + off);
        q2   += bf4_to_f32(*(const u16x4*)(Ph + off));
    }
    float ra = 1.f / (float)(al + 1), ro = 1.f / (float)(ol + 1);
    int sd = sid[row];

    f32x4 x = asum * ra + osum * ro
            + *(const f32x4*)(Wtrip + (size_t)(512 + sd) * 256 + c)
            + *(const f32x4*)(btrip + c);
    *(f32x4*)(node + (size_t)row * 256 + c) = x;

    f32x4 nw = p2 * ra + q2 * ro
             + *(const f32x4*)(W3g + sd * 256 + c)
             + *(const f32x4*)(btg + c);
    u16x4 nwh;
    nwh.x = f_to_bf16(nw.x); nwh.y = f_to_bf16(nw.y);
    nwh.z = f_to_bf16(nw.z); nwh.w = f_to_bf16(nw.w);
    *(u16x4*)(nodeWh + (size_t)row * 256 + c) = nwh;

    f32x4 lx = leaky4(x);
    f32x4 w1 = *(const f32x4*)(Wattn + c);
    f32x4 w2 = *(const f32x4*)(Wattn + 256 + c);
    float s1 = lx.x*w1.x + lx.y*w1.y + lx.z*w1.z + lx.w*w1.w;
    float s2 = lx.x*w2.x + lx.y*w2.y + lx.z*w2.z + lx.w*w2.w;
    #pragma unroll
    for (int o = 32; o; o >>= 1) {
        s1 += __shfl_xor(s1, o);
        s2 += __shfl_xor(s2, o);
    }
    if (lane == 0) { atg[row] = s1; asr[row] = s2; }
}

// ---------------- sparse edges: wave-per-target, XCD-swizzled, zero barriers
//                  bf16 nodeW gather + copy share ----------------
__global__ __launch_bounds__(256) void k_edges(
        const float* __restrict__ node, const unsigned short* __restrict__ nodeWh,
        const float* __restrict__ atg, const float* __restrict__ asr,
        const float* __restrict__ ae, const float* __restrict__ battn,
        const float* __restrict__ ve, const float* __restrict__ bgat,
        const int* __restrict__ keys,
        const float* __restrict__ emb, float* __restrict__ out,
        float* __restrict__ nadd, int* __restrict__ bflag) {
    int bid = blockIdx.x;
    int tid = threadIdx.x;
    int wv = tid >> 6, lane = tid & 63;

    copy_lin(emb, out, 6356992L + (long)bid * 496, 496, tid);

    int s = ((bid & 7) << 9) | (bid >> 3);   // XCD swizzle: 4 whole batches per XCD
    int tgt = (s << 2) + wv;
    int b = tgt >> 9, base = b << 9, lt = tgt & 511;

    int mykey = keys[tgt];
    int ka = mykey >> 10, ko = mykey & 1023;

    unsigned long long mA[8], mO[8];
    #pragma unroll
    for (int j = 0; j < 8; ++j) {
        int ls = (j << 6) + lane;
        int k2 = keys[base + ls];
        bool self = (ls == lt);
        mA[j] = __ballot(((k2 >> 10) == ka) && !self);
        mO[j] = __ballot(((k2 & 1023) == ko) && !self);
    }

    f32x4 xt4 = *(const f32x4*)(node + (size_t)tgt * 256 + (lane << 2));
    float a_t = atg[tgt];
    float ae0 = ae[0], ae1 = ae[1], b0 = battn[0];

    float s0a[8], s1a[8];
    unsigned long long mK[8];
    #pragma unroll
    for (int j = 0; j < 8; ++j) {
        s0a[j] = NEGSENT; s1a[j] = NEGSENT;
        unsigned long long m = mA[j] | mO[j];
        while (m) {
            int bit = __builtin_ctzll(m); m &= m - 1;
            int gs = base + (j << 6) + bit;
            f32x4 y = *(const f32x4*)(node + (size_t)gs * 256 + (lane << 2));
            float p = xt4.x * y.x + xt4.y * y.y + xt4.z * y.z + xt4.w * y.w;
            #pragma unroll
            for (int o = 32; o; o >>= 1) p += __shfl_xor(p, o);
            if (p > 0.f && lane == bit) {
                float bs = a_t + asr[gs] + b0;
                if ((mA[j] >> bit) & 1) s0a[j] = bs + ae0;
                if ((mO[j] >> bit) & 1) s1a[j] = bs + ae1;
            }
        }
        mK[j] = __ballot(s0a[j] > -1e29f || s1a[j] > -1e29f);
    }

    float mx = NEGSENT;
    #pragma unroll
    for (int j = 0; j < 8; ++j) mx = fmaxf(mx, fmaxf(s0a[j], s1a[j]));
    #pragma unroll
    for (int o = 32; o; o >>= 1) mx = fmaxf(mx, __shfl_xor(mx, o));
    bool has = mx > -1e29f;

    float se0 = 0.f, se1 = 0.f;
    #pragma unroll
    for (int j = 0; j < 8; ++j) {
        se0 += expf(s0a[j] - mx);
        se1 += expf(s1a[j] - mx);
    }
    #pragma unroll
    for (int o = 32; o; o >>= 1) { se0 += __shfl_xor(se0, o); se1 += __shfl_xor(se1, o); }
    float rden = 1.f / (se0 + se1);

    f32x4 res;
    if (has) {
        f32x4 agg4 = {0.f, 0.f, 0.f, 0.f};
        #pragma unroll
        for (int j = 0; j < 8; ++j) {
            unsigned long long m = mK[j];
            while (m) {
                int bit = __builtin_ctzll(m); m &= m - 1;
                int gs = base + (j << 6) + bit;
                float w0 = __shfl(s0a[j], bit);
                float w1 = __shfl(s1a[j], bit);
                float wt = (expf(w0 - mx) + expf(w1 - mx)) * rden;
                f32x4 nw = bf4_to_f32(*(const u16x4*)(nodeWh + (size_t)gs * 256 + (lane << 2)));
                agg4.x += wt * nw.x; agg4.y += wt * nw.y;
                agg4.z += wt * nw.z; agg4.w += wt * nw.w;
            }
        }
        f32x4 v1 = *(const f32x4*)(ve + (lane << 2));
        f32x4 v2 = *(const f32x4*)(ve + 256 + (lane << 2));
        f32x4 bg = *(const f32x4*)(bgat + (lane << 2));
        float c0 = se0 * rden, c1 = se1 * rden;
        res.x = fmaxf(agg4.x + c0 * v1.x + c1 * v2.x + bg.x, 0.f);
        res.y = fmaxf(agg4.y + c0 * v1.y + c1 * v2.y + bg.y, 0.f);
        res.z = fmaxf(agg4.z + c0 * v1.z + c1 * v2.z + bg.z, 0.f);
        res.w = fmaxf(agg4.w + c0 * v1.w + c1 * v2.w + bg.w, 0.f);
        if (lane == 0) bflag[b] = 1;
    } else {
        res = xt4;
    }
    *(f32x4*)(nadd + (size_t)tgt * 256 + (lane << 2)) = res;
}

// ---------------- out rows<128: emb + ballot-gathered scatter-add ----------------
__global__ __launch_bounds__(256) void k_scatter(const float* __restrict__ emb,
        const float* __restrict__ nadd,
        const int* __restrict__ ast, const int* __restrict__ ost,
        const int* __restrict__ bflag, float* __restrict__ out) {
    int b = blockIdx.x >> 7;
    int r = blockIdx.x & 127;
    int tid = threadIdx.x;

    __shared__ int cen[512];
    __shared__ unsigned long long s_mask[8];
    for (int n = tid; n < 512; n += 256)
        cen[n] = (ast[(b << 9) + n] + ost[(b << 9) + n]) >> 1;
    __syncthreads();
    #pragma unroll
    for (int p = 0; p < 2; ++p) {
        int n = tid + (p << 8);
        unsigned long long bal = __ballot(cen[n] == r);
        if ((tid & 63) == 0) s_mask[(p << 2) + (tid >> 6)] = bal;
    }
    __syncthreads();
    size_t o = ((size_t)b * Ln + r) * 256 + tid;
    float acc = emb[o];
    if (bflag[b]) {
        for (int w = 0; w < 8; ++w) {
            unsigned long long m = s_mask[w];
            while (m) {
                int n = (w << 6) + __builtin_ctzll(m); m &= m - 1;
                acc += nadd[((size_t)(b << 9) + n) * 256 + tid];
            }
        }
    }
    out[o] = acc;
}

extern "C" void kernel_launch(void* const* d_in, const int* in_sizes, int n_in,
                              void* d_out, int out_size, void* d_ws, size_t ws_size,
                              hipStream_t stream) {
    const float* emb   = (const float*)d_in[0];
    const float* Wtrip = (const float*)d_in[1];
    const float* btrip = (const float*)d_in[2];
    const float* Eemb  = (const float*)d_in[3];
    const float* Wattn = (const float*)d_in[4];
    const float* battn = (const float*)d_in[5];
    const float* Wgat  = (const float*)d_in[6];
    const float* bgat  = (const float*)d_in[7];
    const int* ast  = (const int*)d_in[8];
    const int* alen = (const int*)d_in[9];
    const int* ost  = (const int*)d_in[10];
    const int* olen = (const int*)d_in[11];
    const int* sid  = (const int*)d_in[12];
    float* out = (float*)d_out;

    float* ws    = (float*)d_ws;
    float* PQf   = ws;                                    // [4352*512] fp32
    float* node  = PQf + (size_t)4352 * 512;              // [ROWS*256] fp32
    float* nadd  = node + (size_t)ROWS * 256;             // [ROWS*256] fp32
    float* W3g   = nadd + (size_t)ROWS * 256;             // [3*256]
    float* btg   = W3g + 768;                             // [256]
    float* atg   = btg + 256;                             // [ROWS]
    float* asr   = atg + ROWS;                            // [ROWS]
    float* ae    = asr + ROWS;                            // [2]
    float* ve    = ae + 2;                                // [512]
    int* bflag   = (int*)(ve + 512);                      // [Bn]
    int* keys    = bflag + Bn;                            // [ROWS]
    unsigned short* PQh    = (unsigned short*)(keys + ROWS + 32);   // [4352*512] bf16
    unsigned short* nodeWh = PQh + (size_t)4352 * 512;              // [ROWS*256] bf16
    unsigned short* embh   = nodeWh + (size_t)ROWS * 256;           // [4352*256] bf16
    unsigned short* WtGT   = embh + (size_t)4352 * 256;             // [512*256] bf16

    k_pre<<<1024, 256, 0, stream>>>(Wtrip, btrip, Eemb, Wattn, Wgat,
                                    ast, alen, ost, olen, emb, out,
                                    WtGT, embh, W3g, btg, ae, ve, keys, bflag);
    k_pq<<<dim3(68, 16), 256, 0, stream>>>(emb, Wtrip, embh, WtGT, PQf, PQh, out);
    k_combine<<<ROWS / 4, 256, 0, stream>>>(PQf, PQh, Wtrip, btrip, sid,
                                            ast, alen, ost, olen,
                                            Wattn, W3g, btg, emb, out, node, nodeWh,
                                            atg, asr);
    k_edges<<<ROWS / 4, 256, 0, stream>>>(node, nodeWh, atg, asr, ae, battn, ve, bgat,
                                          keys, emb, out, nadd, bflag);
    k_scatter<<<Bn * 128, 256, 0, stream>>>(emb, nadd, ast, ost, bflag, out);
}

// Round 18
// 130.272 us; speedup vs baseline: 1.3740x; 1.0089x over previous
//
#include <hip/hip_runtime.h>
#include <math.h>

#define Bn 32
#define Ln 4096
#define ROWS 16384
#define LR 136
#define SLOPEC 0.2f
#define NEGSENT -1e30f
// Copy plan: linear [0, 7340032) = batches 0-27 full:
//   k_pre [0, 2097152) | k_pq [2097152, 3211264) | k_combine [3211264, 5308416) 4096x512
//   k_edges [5308416, 7340032) 4096x496
// batches 28-31 heads (rows<128, 32768 slots): k_pre blocks 992-1023 (1024 each)
// batches 28-31 tails (rows>=128, 1015808 slots): k_scatter 4096x248 (no overlap with
//   scatter's row<128 writes). Rows<128 of batches 0-27 overwritten by k_scatter.

typedef __attribute__((ext_vector_type(4))) float f32x4;
typedef __attribute__((ext_vector_type(4))) unsigned short u16x4;
typedef __attribute__((ext_vector_type(8))) short bf16x8;

__device__ __forceinline__ void copy_lin(const float* __restrict__ emb,
        float* __restrict__ out, long start, int count, int tid) {
    const f32x4* s4 = (const f32x4*)emb;
    f32x4* d4 = (f32x4*)out;
    for (int i = tid; i < count; i += 256)
        d4[start + i] = s4[start + i];
}

__device__ __forceinline__ f32x4 leaky4(f32x4 v) {
    f32x4 r;
    r.x = v.x >= 0.f ? v.x : SLOPEC * v.x;
    r.y = v.y >= 0.f ? v.y : SLOPEC * v.y;
    r.z = v.z >= 0.f ? v.z : SLOPEC * v.z;
    r.w = v.w >= 0.f ? v.w : SLOPEC * v.w;
    return r;
}

__device__ __forceinline__ f32x4 bf4_to_f32(u16x4 h) {
    union { unsigned int u; float f; } t;
    f32x4 r;
    t.u = (unsigned)h.x << 16; r.x = t.f;
    t.u = (unsigned)h.y << 16; r.y = t.f;
    t.u = (unsigned)h.z << 16; r.z = t.f;
    t.u = (unsigned)h.w << 16; r.w = t.f;
    return r;
}

__device__ __forceinline__ unsigned short f_to_bf16(float f) {
    union { float f; unsigned int u; } t;
    t.f = f;
    unsigned int u = t.u;
    u += 0x7FFFu + ((u >> 16) & 1u);   // round-to-nearest-even
    return (unsigned short)(u >> 16);
}

// ---------------- pre: WtGT(bf16,T), embh(bf16), W3g, btg, ae, ve, keys, bflag
//                  + copy share + batch28-31 heads (blocks 992-1023) ----------------
__global__ __launch_bounds__(256) void k_pre(const float* __restrict__ Wtrip,
        const float* __restrict__ btrip, const float* __restrict__ Eemb,
        const float* __restrict__ Wattn, const float* __restrict__ Wgat,
        const int* __restrict__ ast, const int* __restrict__ alen,
        const int* __restrict__ ost, const int* __restrict__ olen,
        const float* __restrict__ emb, float* __restrict__ out,
        unsigned short* __restrict__ WtGT, unsigned short* __restrict__ embh,
        float* __restrict__ W3g, float* __restrict__ btg,
        float* __restrict__ ae, float* __restrict__ ve,
        int* __restrict__ keys, int* __restrict__ bflag) {
    int bid = blockIdx.x, tid = threadIdx.x;
    copy_lin(emb, out, (long)bid * 2048, 2048, tid);
    if (bid >= 992) {
        // heads of batches 28-31: 32 blocks x 1024 slots
        const f32x4* s4 = (const f32x4*)emb;
        f32x4* d4 = (f32x4*)out;
        int idx0 = (bid - 992) << 10;
        #pragma unroll
        for (int i = 0; i < 4; ++i) {
            int idx = idx0 + (i << 8) + tid;
            long slot = ((28L + (idx >> 13)) << 18) | (idx & 8191);
            d4[slot] = s4[slot];
        }
    }
    __shared__ float Als[32][68];
    __shared__ float Bls[32][64];
    __shared__ float red[4];
    __shared__ float vr0[8][32], vr1[8][32];
    if (bid < 32) {
        // WtG[mat][h][c] = sum_n Wtrip[mat*256+h][n]*Wgat[n][c]; store bf16 TRANSPOSED
        int mat = bid >> 4, t = bid & 15;
        int m0 = (t >> 2) << 6, n0 = (t & 3) << 6;
        const float* A = Wtrip + mat * 65536;
        int r0 = (tid & 15) << 2, c0 = (tid >> 4) << 2;
        float acc[4][4] = {};
        for (int kk = 0; kk < 256; kk += 32) {
            __syncthreads();
            #pragma unroll
            for (int p = 0; p < 2; ++p) {
                int idx = tid + (p << 8);
                int row = idx >> 3, kq = (idx & 7) << 2;
                const float4 v = *(const float4*)(A + (size_t)(m0 + row) * 256 + kk + kq);
                Als[kq + 0][row] = v.x; Als[kq + 1][row] = v.y;
                Als[kq + 2][row] = v.z; Als[kq + 3][row] = v.w;
            }
            #pragma unroll
            for (int p = 0; p < 2; ++p) {
                int idx = tid + (p << 8);
                int k = idx >> 4, hq = (idx & 15) << 2;
                *(float4*)(&Bls[k][hq]) = *(const float4*)(Wgat + (size_t)(kk + k) * 256 + n0 + hq);
            }
            __syncthreads();
            #pragma unroll
            for (int k = 0; k < 32; ++k) {
                float4 a  = *(const float4*)(&Als[k][r0]);
                float4 bv = *(const float4*)(&Bls[k][c0]);
                acc[0][0] += a.x*bv.x; acc[0][1] += a.x*bv.y; acc[0][2] += a.x*bv.z; acc[0][3] += a.x*bv.w;
                acc[1][0] += a.y*bv.x; acc[1][1] += a.y*bv.y; acc[1][2] += a.y*bv.z; acc[1][3] += a.y*bv.w;
                acc[2][0] += a.z*bv.x; acc[2][1] += a.z*bv.y; acc[2][2] += a.z*bv.z; acc[2][3] += a.z*bv.w;
                acc[3][0] += a.w*bv.x; acc[3][1] += a.w*bv.y; acc[3][2] += a.w*bv.z; acc[3][3] += a.w*bv.w;
            }
        }
        #pragma unroll
        for (int i = 0; i < 4; ++i)
            #pragma unroll
            for (int j = 0; j < 4; ++j)
                WtGT[(size_t)(mat * 256 + n0 + c0 + j) * 256 + m0 + r0 + i] =
                    f_to_bf16(acc[i][j]);
    } else if (bid == 32) {
        float s = 0.f;
        for (int k = 0; k < 256; ++k) s += btrip[k] * Wgat[(size_t)k * 256 + tid];
        btg[tid] = s;
    } else if (bid == 33) {
        if (tid < Bn) bflag[tid] = 0;
        #pragma unroll
        for (int e = 0; e < 2; ++e) {
            float x = Eemb[e * 256 + tid];
            float lx = x >= 0.f ? x : SLOPEC * x;
            float s = lx * Wattn[512 + tid];
            #pragma unroll
            for (int o = 32; o; o >>= 1) s += __shfl_down(s, o);
            if ((tid & 63) == 0) red[tid >> 6] = s;
            __syncthreads();
            if (tid == 0) ae[e] = red[0] + red[1] + red[2] + red[3];
            __syncthreads();
        }
    } else if (bid < 37) {
        int s = bid - 34;
        float acc = 0.f;
        for (int k = 0; k < 256; ++k)
            acc += Wtrip[(size_t)(512 + s) * 256 + k] * Wgat[(size_t)k * 256 + tid];
        W3g[s * 256 + tid] = acc;
    } else if (bid < 45) {
        int j = bid - 37;
        int n0 = j << 5;
        int nl = tid & 31, kg = tid >> 5;
        float p0 = 0.f, p1 = 0.f;
        for (int kk = 0; kk < 32; ++kk) {
            int k = (kg << 5) + kk;
            float w = Wgat[(size_t)(256 + k) * 256 + n0 + nl];
            p0 += Eemb[k] * w;
            p1 += Eemb[256 + k] * w;
        }
        vr0[kg][nl] = p0; vr1[kg][nl] = p1;
        __syncthreads();
        if (tid < 32) {
            float s0 = 0.f, s1 = 0.f;
            #pragma unroll
            for (int g = 0; g < 8; ++g) { s0 += vr0[g][tid]; s1 += vr1[g][tid]; }
            ve[n0 + tid] = s0;
            ve[256 + n0 + tid] = s1;
        }
    } else if (bid < 109) {
        int row = (bid - 45) * 256 + tid;
        keys[row] = (((ast[row] << 3) | alen[row]) << 10) | ((ost[row] << 3) | olen[row]);
    } else if (bid < 381) {
        // embh: bf16 of emb135 [4352][256]; 272 blocks x 16 rows, coalesced
        int rbase = (bid - 109) << 4;
        #pragma unroll
        for (int i = 0; i < 16; ++i) {
            int row = rbase + i;
            int b2 = row / LR, l2 = row - b2 * LR;
            embh[(size_t)row * 256 + tid] =
                f_to_bf16(emb[((size_t)b2 * Ln + l2) * 256 + tid]);
        }
    }
}

// ---------------- k_pq: j<8 fp32 tile GEMM -> PQf (sign path)
//                  j>=8 bf16 MFMA (embh @ WtGT^T) -> PQh (agg path)
//                  + copy share ----------------
__global__ __launch_bounds__(256) void k_pq(const float* __restrict__ emb,
        const float* __restrict__ Wtrip,
        const unsigned short* __restrict__ embh, const unsigned short* __restrict__ WtGT,
        float* __restrict__ PQf, unsigned short* __restrict__ PQh,
        float* __restrict__ out) {
    __shared__ float Als[32][68];
    __shared__ float Bls[32][64];
    int tid = threadIdx.x;
    {
        int bid = blockIdx.y * 68 + blockIdx.x;   // 1088 blocks x 1024 slots
        copy_lin(emb, out, 2097152L + (long)bid * 1024, 1024, tid);
    }
    int m0 = blockIdx.x << 6;
    int j = blockIdx.y;   // n-tile 0..15

    if (j < 8) {
        const float* Bp = Wtrip + ((j < 4) ? (j << 6) : (65536 + ((j - 4) << 6)));
        int r0 = (tid & 15) << 2;
        int c0 = (tid >> 4) << 2;
        float acc[4][4] = {};
        for (int kk = 0; kk < 256; kk += 32) {
            __syncthreads();
            #pragma unroll
            for (int p = 0; p < 2; ++p) {   // A: 64 rows x 32 k (k-major LDS)
                int idx = tid + (p << 8);
                int row = idx >> 3;
                int kq = (idx & 7) << 2;
                int m = m0 + row;
                int b = m / LR;
                int l = m - b * LR;
                const float4 v = *(const float4*)(emb + (size_t)(b * Ln + l) * 256 + kk + kq);
                Als[kq + 0][row] = v.x; Als[kq + 1][row] = v.y;
                Als[kq + 2][row] = v.z; Als[kq + 3][row] = v.w;
            }
            #pragma unroll
            for (int p = 0; p < 2; ++p) {   // B: 32 k x 64 cols
                int idx = tid + (p << 8);
                int k = idx >> 4;
                int hq = (idx & 15) << 2;
                *(float4*)(&Bls[k][hq]) = *(const float4*)(Bp + (size_t)(kk + k) * 256 + hq);
            }
            __syncthreads();
            #pragma unroll
            for (int k = 0; k < 32; ++k) {
                float4 a  = *(const float4*)(&Als[k][r0]);
                float4 bv = *(const float4*)(&Bls[k][c0]);
                acc[0][0] += a.x*bv.x; acc[0][1] += a.x*bv.y; acc[0][2] += a.x*bv.z; acc[0][3] += a.x*bv.w;
                acc[1][0] += a.y*bv.x; acc[1][1] += a.y*bv.y; acc[1][2] += a.y*bv.z; acc[1][3] += a.y*bv.w;
                acc[2][0] += a.z*bv.x; acc[2][1] += a.z*bv.y; acc[2][2] += a.z*bv.z; acc[2][3] += a.z*bv.w;
                acc[3][0] += a.w*bv.x; acc[3][1] += a.w*bv.y; acc[3][2] += a.w*bv.z; acc[3][3] += a.w*bv.w;
            }
        }
        #pragma unroll
        for (int i = 0; i < 4; ++i)
            #pragma unroll
            for (int jj = 0; jj < 4; ++jj)
                PQf[(size_t)(m0 + r0 + i) * 512 + (j << 6) + c0 + jj] = acc[i][jj];
    } else {
        int jn = j - 8;
        int wv = tid >> 6, lane = tid & 63;
        int m0w = m0 + (wv << 4);
        int n0 = jn << 6;
        int fr = lane & 15;
        int kq = (lane >> 4) << 3;
        f32x4 acc2[4] = {};
        for (int k0 = 0; k0 < 256; k0 += 32) {
            bf16x8 a = *(const bf16x8*)(embh + (size_t)(m0w + fr) * 256 + k0 + kq);
            #pragma unroll
            for (int nf = 0; nf < 4; ++nf) {
                bf16x8 bfr = *(const bf16x8*)(WtGT + (size_t)(n0 + (nf << 4) + fr) * 256 + k0 + kq);
                acc2[nf] = __builtin_amdgcn_mfma_f32_16x16x32_bf16(a, bfr, acc2[nf], 0, 0, 0);
            }
        }
        int r0w = (lane >> 4) << 2;
        #pragma unroll
        for (int nf = 0; nf < 4; ++nf)
            #pragma unroll
            for (int r = 0; r < 4; ++r)
                PQh[(size_t)(m0w + r0w + r) * 512 + n0 + (nf << 4) + fr] =
                    f_to_bf16(acc2[nf][r]);
    }
}

// ---------------- combine: wave-per-row, XCD-swizzled, no barriers
//                  -> node (fp32), nodeWh (bf16), atg, asr + copy share ----------------
__global__ __launch_bounds__(256) void k_combine(const float* __restrict__ PQf,
        const unsigned short* __restrict__ PQh,
        const float* __restrict__ Wtrip, const float* __restrict__ btrip,
        const int* __restrict__ sid,
        const int* __restrict__ ast, const int* __restrict__ alen,
        const int* __restrict__ ost, const int* __restrict__ olen,
        const float* __restrict__ Wattn, const float* __restrict__ W3g,
        const float* __restrict__ btg, const float* __restrict__ emb,
        float* __restrict__ out, float* __restrict__ node,
        unsigned short* __restrict__ nodeWh,
        float* __restrict__ atg, float* __restrict__ asr) {
    int bid = blockIdx.x, tid = threadIdx.x;
    int wv = tid >> 6, lane = tid & 63;
    copy_lin(emb, out, 3211264L + (long)bid * 512, 512, tid);

    int s = ((bid & 7) << 9) | (bid >> 3);   // XCD swizzle: 4 whole batches per XCD
    int row = (s << 2) + wv;
    int b = row >> 9;
    int as_ = ast[row], al = alen[row];
    int os_ = ost[row], ol = olen[row];
    int c = lane << 2;
    const float* Pb = PQf + (size_t)b * LR * 512 + c;
    const unsigned short* Ph = PQh + (size_t)b * LR * 512 + c;

    f32x4 asum = {0.f,0.f,0.f,0.f}, osum = asum, p2 = asum, q2 = asum;
    for (int i = 0; i <= al; ++i) {
        size_t off = (size_t)(as_ + i) * 512;
        asum += *(const f32x4*)(Pb + off);
        p2   += bf4_to_f32(*(const u16x4*)(Ph + off));
    }
    for (int i = 0; i <= ol; ++i) {
        size_t off = (size_t)(os_ + i) * 512 + 256;
        osum += *(const f32x4*)(Pb + off);
        q2   += bf4_to_f32(*(const u16x4*)(Ph + off));
    }
    float ra = 1.f / (float)(al + 1), ro = 1.f / (float)(ol + 1);
    int sd = sid[row];

    f32x4 x = asum * ra + osum * ro
            + *(const f32x4*)(Wtrip + (size_t)(512 + sd) * 256 + c)
            + *(const f32x4*)(btrip + c);
    *(f32x4*)(node + (size_t)row * 256 + c) = x;

    f32x4 nw = p2 * ra + q2 * ro
             + *(const f32x4*)(W3g + sd * 256 + c)
             + *(const f32x4*)(btg + c);
    u16x4 nwh;
    nwh.x = f_to_bf16(nw.x); nwh.y = f_to_bf16(nw.y);
    nwh.z = f_to_bf16(nw.z); nwh.w = f_to_bf16(nw.w);
    *(u16x4*)(nodeWh + (size_t)row * 256 + c) = nwh;

    f32x4 lx = leaky4(x);
    f32x4 w1 = *(const f32x4*)(Wattn + c);
    f32x4 w2 = *(const f32x4*)(Wattn + 256 + c);
    float s1 = lx.x*w1.x + lx.y*w1.y + lx.z*w1.z + lx.w*w1.w;
    float s2 = lx.x*w2.x + lx.y*w2.y + lx.z*w2.z + lx.w*w2.w;
    #pragma unroll
    for (int o = 32; o; o >>= 1) {
        s1 += __shfl_xor(s1, o);
        s2 += __shfl_xor(s2, o);
    }
    if (lane == 0) { atg[row] = s1; asr[row] = s2; }
}

// ---------------- sparse edges: wave-per-target, XCD-swizzled, zero barriers
//                  bf16 nodeW gather, bf16 nadd write + copy share ----------------
__global__ __launch_bounds__(256) void k_edges(
        const float* __restrict__ node, const unsigned short* __restrict__ nodeWh,
        const float* __restrict__ atg, const float* __restrict__ asr,
        const float* __restrict__ ae, const float* __restrict__ battn,
        const float* __restrict__ ve, const float* __restrict__ bgat,
        const int* __restrict__ keys,
        const float* __restrict__ emb, float* __restrict__ out,
        unsigned short* __restrict__ naddh, int* __restrict__ bflag) {
    int bid = blockIdx.x;
    int tid = threadIdx.x;
    int wv = tid >> 6, lane = tid & 63;

    copy_lin(emb, out, 5308416L + (long)bid * 496, 496, tid);

    int s = ((bid & 7) << 9) | (bid >> 3);   // XCD swizzle: 4 whole batches per XCD
    int tgt = (s << 2) + wv;
    int b = tgt >> 9, base = b << 9, lt = tgt & 511;

    int mykey = keys[tgt];
    int ka = mykey >> 10, ko = mykey & 1023;

    unsigned long long mA[8], mO[8];
    #pragma unroll
    for (int j = 0; j < 8; ++j) {
        int ls = (j << 6) + lane;
        int k2 = keys[base + ls];
        bool self = (ls == lt);
        mA[j] = __ballot(((k2 >> 10) == ka) && !self);
        mO[j] = __ballot(((k2 & 1023) == ko) && !self);
    }

    f32x4 xt4 = *(const f32x4*)(node + (size_t)tgt * 256 + (lane << 2));
    float a_t = atg[tgt];
    float ae0 = ae[0], ae1 = ae[1], b0 = battn[0];

    float s0a[8], s1a[8];
    unsigned long long mK[8];
    #pragma unroll
    for (int j = 0; j < 8; ++j) {
        s0a[j] = NEGSENT; s1a[j] = NEGSENT;
        unsigned long long m = mA[j] | mO[j];
        while (m) {
            int bit = __builtin_ctzll(m); m &= m - 1;
            int gs = base + (j << 6) + bit;
            f32x4 y = *(const f32x4*)(node + (size_t)gs * 256 + (lane << 2));
            float p = xt4.x * y.x + xt4.y * y.y + xt4.z * y.z + xt4.w * y.w;
            #pragma unroll
            for (int o = 32; o; o >>= 1) p += __shfl_xor(p, o);
            if (p > 0.f && lane == bit) {
                float bs = a_t + asr[gs] + b0;
                if ((mA[j] >> bit) & 1) s0a[j] = bs + ae0;
                if ((mO[j] >> bit) & 1) s1a[j] = bs + ae1;
            }
        }
        mK[j] = __ballot(s0a[j] > -1e29f || s1a[j] > -1e29f);
    }

    float mx = NEGSENT;
    #pragma unroll
    for (int j = 0; j < 8; ++j) mx = fmaxf(mx, fmaxf(s0a[j], s1a[j]));
    #pragma unroll
    for (int o = 32; o; o >>= 1) mx = fmaxf(mx, __shfl_xor(mx, o));
    bool has = mx > -1e29f;

    float se0 = 0.f, se1 = 0.f;
    #pragma unroll
    for (int j = 0; j < 8; ++j) {
        se0 += expf(s0a[j] - mx);
        se1 += expf(s1a[j] - mx);
    }
    #pragma unroll
    for (int o = 32; o; o >>= 1) { se0 += __shfl_xor(se0, o); se1 += __shfl_xor(se1, o); }
    float rden = 1.f / (se0 + se1);

    f32x4 res;
    if (has) {
        f32x4 agg4 = {0.f, 0.f, 0.f, 0.f};
        #pragma unroll
        for (int j = 0; j < 8; ++j) {
            unsigned long long m = mK[j];
            while (m) {
                int bit = __builtin_ctzll(m); m &= m - 1;
                int gs = base + (j << 6) + bit;
                float w0 = __shfl(s0a[j], bit);
                float w1 = __shfl(s1a[j], bit);
                float wt = (expf(w0 - mx) + expf(w1 - mx)) * rden;
                f32x4 nw = bf4_to_f32(*(const u16x4*)(nodeWh + (size_t)gs * 256 + (lane << 2)));
                agg4.x += wt * nw.x; agg4.y += wt * nw.y;
                agg4.z += wt * nw.z; agg4.w += wt * nw.w;
            }
        }
        f32x4 v1 = *(const f32x4*)(ve + (lane << 2));
        f32x4 v2 = *(const f32x4*)(ve + 256 + (lane << 2));
        f32x4 bg = *(const f32x4*)(bgat + (lane << 2));
        float c0 = se0 * rden, c1 = se1 * rden;
        res.x = fmaxf(agg4.x + c0 * v1.x + c1 * v2.x + bg.x, 0.f);
        res.y = fmaxf(agg4.y + c0 * v1.y + c1 * v2.y + bg.y, 0.f);
        res.z = fmaxf(agg4.z + c0 * v1.z + c1 * v2.z + bg.z, 0.f);
        res.w = fmaxf(agg4.w + c0 * v1.w + c1 * v2.w + bg.w, 0.f);
        if (lane == 0) bflag[b] = 1;
    } else {
        res = xt4;
    }
    u16x4 rh;
    rh.x = f_to_bf16(res.x); rh.y = f_to_bf16(res.y);
    rh.z = f_to_bf16(res.z); rh.w = f_to_bf16(res.w);
    *(u16x4*)(naddh + (size_t)tgt * 256 + (lane << 2)) = rh;
}

// ---------------- out rows<128: emb + ballot-gathered scatter-add (bf16 nadd)
//                  + copy share (tails of batches 28-31) ----------------
__global__ __launch_bounds__(256) void k_scatter(const float* __restrict__ emb,
        const unsigned short* __restrict__ naddh,
        const int* __restrict__ ast, const int* __restrict__ ost,
        const int* __restrict__ bflag, float* __restrict__ out) {
    int b = blockIdx.x >> 7;
    int r = blockIdx.x & 127;
    int tid = threadIdx.x;

    {   // copy: tails (rows>=128) of batches 28-31; 4096 blocks x 248 slots
        const f32x4* s4 = (const f32x4*)emb;
        f32x4* d4 = (f32x4*)out;
        if (tid < 248) {
            int s2 = blockIdx.x * 248 + tid;
            int bb = (s2 >= 253952) + (s2 >= 507904) + (s2 >= 761856);
            long slot = ((28L + bb) << 18) + 8192 + (s2 - bb * 253952);
            d4[slot] = s4[slot];
        }
    }

    __shared__ int cen[512];
    __shared__ unsigned long long s_mask[8];
    for (int n = tid; n < 512; n += 256)
        cen[n] = (ast[(b << 9) + n] + ost[(b << 9) + n]) >> 1;
    __syncthreads();
    #pragma unroll
    for (int p = 0; p < 2; ++p) {
        int n = tid + (p << 8);
        unsigned long long bal = __ballot(cen[n] == r);
        if ((tid & 63) == 0) s_mask[(p << 2) + (tid >> 6)] = bal;
    }
    __syncthreads();
    size_t o = ((size_t)b * Ln + r) * 256 + tid;
    float acc = emb[o];
    if (bflag[b]) {
        union { unsigned int u; float f; } t;
        for (int w = 0; w < 8; ++w) {
            unsigned long long m = s_mask[w];
            while (m) {
                int n = (w << 6) + __builtin_ctzll(m); m &= m - 1;
                t.u = (unsigned)naddh[((size_t)(b << 9) + n) * 256 + tid] << 16;
                acc += t.f;
            }
        }
    }
    out[o] = acc;
}

extern "C" void kernel_launch(void* const* d_in, const int* in_sizes, int n_in,
                              void* d_out, int out_size, void* d_ws, size_t ws_size,
                              hipStream_t stream) {
    const float* emb   = (const float*)d_in[0];
    const float* Wtrip = (const float*)d_in[1];
    const float* btrip = (const float*)d_in[2];
    const float* Eemb  = (const float*)d_in[3];
    const float* Wattn = (const float*)d_in[4];
    const float* battn = (const float*)d_in[5];
    const float* Wgat  = (const float*)d_in[6];
    const float* bgat  = (const float*)d_in[7];
    const int* ast  = (const int*)d_in[8];
    const int* alen = (const int*)d_in[9];
    const int* ost  = (const int*)d_in[10];
    const int* olen = (const int*)d_in[11];
    const int* sid  = (const int*)d_in[12];
    float* out = (float*)d_out;

    float* ws    = (float*)d_ws;
    float* PQf   = ws;                                    // [4352*512] fp32
    float* node  = PQf + (size_t)4352 * 512;              // [ROWS*256] fp32
    float* W3g   = node + (size_t)ROWS * 256;             // [3*256]
    float* btg   = W3g + 768;                             // [256]
    float* atg   = btg + 256;                             // [ROWS]
    float* asr   = atg + ROWS;                            // [ROWS]
    float* ae    = asr + ROWS;                            // [2]
    float* ve    = ae + 2;                                // [512]
    int* bflag   = (int*)(ve + 512);                      // [Bn]
    int* keys    = bflag + Bn;                            // [ROWS]
    unsigned short* PQh    = (unsigned short*)(keys + ROWS + 32);   // [4352*512] bf16
    unsigned short* nodeWh = PQh + (size_t)4352 * 512;              // [ROWS*256] bf16
    unsigned short* naddh  = nodeWh + (size_t)ROWS * 256;           // [ROWS*256] bf16
    unsigned short* embh   = naddh + (size_t)ROWS * 256;            // [4352*256] bf16
    unsigned short* WtGT   = embh + (size_t)4352 * 256;             // [512*256] bf16

    k_pre<<<1024, 256, 0, stream>>>(Wtrip, btrip, Eemb, Wattn, Wgat,
                                    ast, alen, ost, olen, emb, out,
                                    WtGT, embh, W3g, btg, ae, ve, keys, bflag);
    k_pq<<<dim3(68, 16), 256, 0, stream>>>(emb, Wtrip, embh, WtGT, PQf, PQh, out);
    k_combine<<<ROWS / 4, 256, 0, stream>>>(PQf, PQh, Wtrip, btrip, sid,
                                            ast, alen, ost, olen,
                                            Wattn, W3g, btg, emb, out, node, nodeWh,
                                            atg, asr);
    k_edges<<<ROWS / 4, 256, 0, stream>>>(node, nodeWh, atg, asr, ae, battn, ve, bgat,
                                          keys, emb, out, naddh, bflag);
    k_scatter<<<Bn * 128, 256, 0, stream>>>(emb, naddh, ast, ost, bflag, out);
}